// Round 1
// 406.101 us; speedup vs baseline: 1.2427x; 1.2427x over previous
//
#include <hip/hip_runtime.h>
#include <math.h>

#define BB 4
#define NN 4096
#define KNNK 16
#define DD 128
#define BN (BB*NN)

typedef __attribute__((ext_vector_type(8))) short short8;   // 8 bf16
typedef __attribute__((ext_vector_type(4))) float floatx4;  // MFMA acc

__device__ __forceinline__ short f2bf(float x) {
  unsigned u = __float_as_uint(x);
  unsigned r = (u + 0x7fffu + ((u >> 16) & 1u)) >> 16;
  return (short)r;
}

__device__ __forceinline__ float bf2f(short h) {
  return __uint_as_float((unsigned)(unsigned short)h << 16);
}

// ---------------------------------------------------------------------------
// mv16: acc[p] += sum_f A[p][f] * W[f*128 + t]  (A in LDS, wave-broadcast reads)
// (still used by the epilogue kernel)
// ---------------------------------------------------------------------------
__device__ __forceinline__ void mv16(const float* __restrict__ Wcol,
                                     const float* __restrict__ A,
                                     float acc[16]) {
#pragma unroll 2
  for (int f4 = 0; f4 < 32; ++f4) {
    float w0 = Wcol[(4 * f4 + 0) * 128];
    float w1 = Wcol[(4 * f4 + 1) * 128];
    float w2 = Wcol[(4 * f4 + 2) * 128];
    float w3 = Wcol[(4 * f4 + 3) * 128];
#pragma unroll
    for (int p = 0; p < 16; ++p) {
      float4 a = *reinterpret_cast<const float4*>(A + p * 128 + 4 * f4);
      acc[p] = fmaf(a.w, w3, fmaf(a.z, w2, fmaf(a.y, w1, fmaf(a.x, w0, acc[p]))));
    }
  }
}

// ---------------------------------------------------------------------------
// KNN v4: one WAVE per query, register-only (verified structure, unchanged).
// ---------------------------------------------------------------------------
__device__ __forceinline__ void ced(double& a, double& b) {
  double mn = fmin(a, b);
  double mx = fmax(a, b);
  a = mn;
  b = mx;
}

__device__ __forceinline__ void dsort16(double v[16]) {
#define CE(i, j) ced(v[i], v[j]);
  CE(0, 1) CE(2, 3) CE(4, 5) CE(6, 7) CE(8, 9) CE(10, 11) CE(12, 13) CE(14, 15)
  CE(0, 2) CE(1, 3) CE(4, 6) CE(5, 7) CE(8, 10) CE(9, 11) CE(12, 14) CE(13, 15)
  CE(1, 2) CE(5, 6) CE(9, 10) CE(13, 14)
  CE(0, 4) CE(1, 5) CE(2, 6) CE(3, 7) CE(8, 12) CE(9, 13) CE(10, 14) CE(11, 15)
  CE(2, 4) CE(3, 5) CE(10, 12) CE(11, 13)
  CE(1, 2) CE(3, 4) CE(5, 6) CE(9, 10) CE(11, 12) CE(13, 14)
  CE(0, 8) CE(1, 9) CE(2, 10) CE(3, 11) CE(4, 12) CE(5, 13) CE(6, 14) CE(7, 15)
  CE(4, 8) CE(5, 9) CE(6, 10) CE(7, 11)
  CE(2, 4) CE(3, 5) CE(6, 8) CE(7, 9) CE(10, 12) CE(11, 13)
  CE(1, 2) CE(3, 4) CE(5, 6) CE(7, 8) CE(9, 10) CE(11, 12) CE(13, 14)
#undef CE
}

// sort a 16-element bitonic sequence ascending
__device__ __forceinline__ void dbitonic16(double m[16]) {
#pragma unroll
  for (int s = 8; s >= 1; s >>= 1) {
#pragma unroll
    for (int i = 0; i < 16; ++i) {
      if ((i & s) == 0) ced(m[i], m[i + s]);
    }
  }
}

__global__ __launch_bounds__(256, 4) void knn_kernel(const float* __restrict__ xyz,
                                                     int* __restrict__ knn) {
  const int wv = threadIdx.x >> 6;
  const int lane = threadIdx.x & 63;
  const int q = blockIdx.x * 4 + wv;
  const int b = q >> 12;
  const int n = q & 4095;
  const float* xb = xyz + (size_t)b * NN * 3;

  const float qx = xb[n * 3 + 0], qy = xb[n * 3 + 1], qz = xb[n * 3 + 2];
  const float qsq = __fadd_rn(__fadd_rn(__fmul_rn(qx, qx), __fmul_rn(qy, qy)),
                              __fmul_rn(qz, qz));

  double top[16];
#pragma unroll
  for (int batch = 0; batch < 4; ++batch) {
    double v[16];
#pragma unroll
    for (int i = 0; i < 16; ++i) {
      const int c = (batch * 16 + i) * 64 + lane;
      float cx = xb[c * 3 + 0], cy = xb[c * 3 + 1], cz = xb[c * 3 + 2];
      float csq = __fadd_rn(__fadd_rn(__fmul_rn(cx, cx), __fmul_rn(cy, cy)),
                            __fmul_rn(cz, cz));
      float dot = __fadd_rn(__fadd_rn(__fmul_rn(qx, cx), __fmul_rn(qy, cy)),
                            __fmul_rn(qz, cz));
      float d = __fadd_rn(__fsub_rn(qsq, __fmul_rn(2.0f, dot)), csq);
      unsigned u = __float_as_uint(d);
      u = (u & 0x80000000u) ? ~u : (u | 0x80000000u);  // monotone float->uint
      unsigned long long key =
          0x3FF0000000000000ULL | (((unsigned long long)u << 12) | (unsigned)c);
      v[i] = __longlong_as_double((long long)key);
    }
    dsort16(v);
    if (batch == 0) {
#pragma unroll
      for (int i = 0; i < 16; ++i) top[i] = v[i];
    } else {
      double m[16];
#pragma unroll
      for (int i = 0; i < 16; ++i)
        m[i] = fmin(top[i], v[15 - i]);  // min(asc, desc) -> bitonic lower half
      dbitonic16(m);
#pragma unroll
      for (int i = 0; i < 16; ++i) top[i] = m[i];
    }
  }

#pragma unroll
  for (int mask = 1; mask <= 32; mask <<= 1) {
    double oth[16];
#pragma unroll
    for (int i = 0; i < 16; ++i) {
      double y = __shfl_xor(top[15 - i], mask);
      oth[i] = fmin(y, top[i]);
    }
    dbitonic16(oth);
#pragma unroll
    for (int i = 0; i < 16; ++i) top[i] = oth[i];
  }

  if (lane == 0) {
    int* outp = knn + (size_t)q * KNNK;
#pragma unroll
    for (int k = 0; k < 16; ++k)
      outp[k] = (int)(__double_as_longlong(top[k]) & 0xFFFLL);
  }
}

// ---------------------------------------------------------------------------
// Weight pre-swizzle (attention stages): Wd2/Wg1/Wg2 (fp32 [k][n]) -> bf16
// B-fragment order for mfma_f32_16x16x32_bf16. Unchanged.
// ---------------------------------------------------------------------------
__global__ void swz_kernel(const float* __restrict__ Wd2,
                           const float* __restrict__ Wg1,
                           const float* __restrict__ Wg2,
                           short* __restrict__ wsw) {
  int t = blockIdx.x * 256 + threadIdx.x;  // [0, 6144): [stage][nt][ks][lane]
  if (t >= 3 * 2048) return;
  int stage = t / 2048;
  int rem = t % 2048;
  int nt = rem / 256;
  int ks = (rem % 256) / 64;
  int lane = rem % 64;
  const float* W = (stage == 0) ? Wd2 : (stage == 1) ? Wg1 : Wg2;
  short8 o;
#pragma unroll
  for (int j = 0; j < 8; ++j) {
    int k = ks * 32 + (lane >> 4) * 8 + j;
    int n = nt * 16 + (lane & 15);
    o[j] = f2bf(W[k * 128 + n]);
  }
  *reinterpret_cast<short8*>(wsw + (size_t)t * 8) = o;
}

// ---------------------------------------------------------------------------
// Weight pre-swizzle + bf16x2 SPLIT for the point-MLP projections:
// W0b, W1, Wq, Wk, Wv (fp32 [k(128)][n(128)]) -> {hi, lo} bf16 B-fragments.
// hi = bf16(w), lo = bf16(w - float(hi)): together >=22 mantissa bits.
// Layout: wsplit[mat*2+half][nt][ks][lane][j], fragment index identical to
// the verified swz_kernel layout.
// ---------------------------------------------------------------------------
__global__ void swz2_kernel(const float* __restrict__ W0b,
                            const float* __restrict__ W1,
                            const float* __restrict__ Wq,
                            const float* __restrict__ Wk,
                            const float* __restrict__ Wv,
                            short* __restrict__ wsplit) {
  int t = blockIdx.x * 256 + threadIdx.x;  // [0, 5*2048)
  if (t >= 5 * 2048) return;
  int mat = t / 2048;
  int rem = t % 2048;
  int lane = rem % 64;
  const float* W = (mat == 0) ? W0b : (mat == 1) ? W1 : (mat == 2) ? Wq
                   : (mat == 3) ? Wk : Wv;
  short8 hi, lo;
#pragma unroll
  for (int j = 0; j < 8; ++j) {
    int ks = (rem % 256) / 64;
    int nt = rem / 256;
    int k = ks * 32 + (lane >> 4) * 8 + j;
    int n = nt * 16 + (lane & 15);
    float w = W[k * 128 + n];
    short h = f2bf(w);
    hi[j] = h;
    lo[j] = f2bf(w - bf2f(h));
  }
  *reinterpret_cast<short8*>(wsplit + ((size_t)(2 * mat) * 2048 + rem) * 8) = hi;
  *reinterpret_cast<short8*>(wsplit + ((size_t)(2 * mat + 1) * 2048 + rem) * 8) = lo;
}

// ---------------------------------------------------------------------------
// Point-MLP on matrix cores (bf16x2 split, fp32-equivalent accuracy).
// Block = 16 points, 4 waves. Each wave owns 2 of the 8 N-tiles (nt0, nt0+1);
// M=16 rows, K=128 (4 MFMA K-steps). Per tile: 3 MFMAs (Ah*Bh, Ah*Bl, Al*Bh).
// Stage chain: fc0a (VALU, K=3) -> fc0b (+pre store) -> fc1 -> q/k/v.
// Transitions: fp32 via LDS trans[16][132] (stride 132 -> balanced banks),
// 8x ds_read_b128 per wave per transition (vs 512 broadcast reads before).
// ---------------------------------------------------------------------------
__global__ __launch_bounds__(256, 4) void point_mlp_mfma_kernel(
    const float* __restrict__ xyz, const float* __restrict__ W0a,
    const float* __restrict__ b0a, const float* __restrict__ b0b,
    const float* __restrict__ b1, const short* __restrict__ wsplit,
    float* __restrict__ pre, float* __restrict__ qv, float* __restrict__ kv,
    float* __restrict__ vv) {
  const int wv = threadIdx.x >> 6;
  const int lane = threadIdx.x & 63;
  const int g = lane >> 4;   // A-frag k-group / D row-group
  const int c = lane & 15;   // A-frag row / D column-in-tile
  const int g0 = blockIdx.x * 16;
  const int nt0 = wv * 2;

  __shared__ __attribute__((aligned(16))) float trans[16 * 132];
  __shared__ float xs[64];
  if (threadIdx.x < 48) {
    int p = threadIdx.x / 3, cc = threadIdx.x % 3;
    xs[p * 4 + cc] = xyz[(size_t)(g0 + p) * 3 + cc];
  }
  __syncthreads();

  short8 ah[4], al[4];
  // ---- fc0a: relu(xyz @ W0a + b0a), computed directly as split A-frags ----
  {
    const float x0 = xs[c * 4 + 0], x1 = xs[c * 4 + 1], x2 = xs[c * 4 + 2];
#pragma unroll
    for (int s = 0; s < 4; ++s) {
#pragma unroll
      for (int j = 0; j < 8; ++j) {
        const int k = s * 32 + g * 8 + j;
        float v = fmaf(x2, W0a[256 + k],
                       fmaf(x1, W0a[128 + k], fmaf(x0, W0a[k], b0a[k])));
        v = fmaxf(v, 0.f);
        const short h = f2bf(v);
        ah[s][j] = h;
        al[s][j] = f2bf(v - bf2f(h));
      }
    }
  }

#define DOGEMM(mat)                                                            \
  {                                                                            \
    const short* Bh = wsplit + (size_t)(2 * (mat)) * 16384;                    \
    const short* Bl = Bh + 16384;                                              \
    _Pragma("unroll") for (int ks = 0; ks < 4; ++ks) {                         \
      const size_t o0 = ((size_t)((nt0 + 0) * 4 + ks) * 64 + lane) * 8;        \
      const size_t o1 = ((size_t)((nt0 + 1) * 4 + ks) * 64 + lane) * 8;        \
      short8 bh0 = *reinterpret_cast<const short8*>(Bh + o0);                  \
      short8 bl0 = *reinterpret_cast<const short8*>(Bl + o0);                  \
      short8 bh1 = *reinterpret_cast<const short8*>(Bh + o1);                  \
      short8 bl1 = *reinterpret_cast<const short8*>(Bl + o1);                  \
      acc0 = __builtin_amdgcn_mfma_f32_16x16x32_bf16(ah[ks], bh0, acc0, 0, 0, 0); \
      acc1 = __builtin_amdgcn_mfma_f32_16x16x32_bf16(ah[ks], bh1, acc1, 0, 0, 0); \
      acc0 = __builtin_amdgcn_mfma_f32_16x16x32_bf16(ah[ks], bl0, acc0, 0, 0, 0); \
      acc1 = __builtin_amdgcn_mfma_f32_16x16x32_bf16(ah[ks], bl1, acc1, 0, 0, 0); \
      acc0 = __builtin_amdgcn_mfma_f32_16x16x32_bf16(al[ks], bh0, acc0, 0, 0, 0); \
      acc1 = __builtin_amdgcn_mfma_f32_16x16x32_bf16(al[ks], bh1, acc1, 0, 0, 0); \
    }                                                                          \
  }

#define SPLITLD()                                                              \
  _Pragma("unroll") for (int s = 0; s < 4; ++s) {                              \
    const float* p_ = &trans[c * 132 + s * 32 + g * 8];                        \
    float4 u0 = *reinterpret_cast<const float4*>(p_);                          \
    float4 u1 = *reinterpret_cast<const float4*>(p_ + 4);                      \
    float tmp[8] = {u0.x, u0.y, u0.z, u0.w, u1.x, u1.y, u1.z, u1.w};           \
    _Pragma("unroll") for (int j = 0; j < 8; ++j) {                            \
      short h_ = f2bf(tmp[j]);                                                 \
      ah[s][j] = h_;                                                           \
      al[s][j] = f2bf(tmp[j] - bf2f(h_));                                      \
    }                                                                          \
  }

  floatx4 acc0, acc1;
  const floatx4 zf = (floatx4){0.f, 0.f, 0.f, 0.f};

  // ---- fc0b: pre = A @ W0b + b0b (no relu; pre stored fp32) ----
  acc0 = zf; acc1 = zf;
  DOGEMM(0);
  {
    const float bb0 = b0b[nt0 * 16 + c];
    const float bb1 = b0b[(nt0 + 1) * 16 + c];
#pragma unroll
    for (int r = 0; r < 4; ++r) {
      const int row = g * 4 + r;
      float v0 = acc0[r] + bb0;
      float v1 = acc1[r] + bb1;
      pre[(size_t)(g0 + row) * 128 + nt0 * 16 + c] = v0;
      pre[(size_t)(g0 + row) * 128 + (nt0 + 1) * 16 + c] = v1;
      trans[row * 132 + nt0 * 16 + c] = v0;
      trans[row * 132 + (nt0 + 1) * 16 + c] = v1;
    }
  }
  __syncthreads();
  SPLITLD();
  __syncthreads();

  // ---- fc1: x = pre @ W1 + b1 ----
  acc0 = zf; acc1 = zf;
  DOGEMM(1);
  {
    const float bb0 = b1[nt0 * 16 + c];
    const float bb1 = b1[(nt0 + 1) * 16 + c];
#pragma unroll
    for (int r = 0; r < 4; ++r) {
      const int row = g * 4 + r;
      trans[row * 132 + nt0 * 16 + c] = acc0[r] + bb0;
      trans[row * 132 + (nt0 + 1) * 16 + c] = acc1[r] + bb1;
    }
  }
  __syncthreads();
  SPLITLD();
  __syncthreads();

#define GSTORE(dst)                                                            \
  _Pragma("unroll") for (int r = 0; r < 4; ++r) {                              \
    const int row = g0 + g * 4 + r;                                            \
    dst[(size_t)row * 128 + nt0 * 16 + c] = acc0[r];                           \
    dst[(size_t)row * 128 + (nt0 + 1) * 16 + c] = acc1[r];                     \
  }

  // ---- q / k / v projections (no bias) ----
  acc0 = zf; acc1 = zf;
  DOGEMM(2);
  GSTORE(qv);

  acc0 = zf; acc1 = zf;
  DOGEMM(3);
  GSTORE(kv);

  acc0 = zf; acc1 = zf;
  DOGEMM(4);
  GSTORE(vv);

#undef DOGEMM
#undef SPLITLD
#undef GSTORE
}

// ---------------------------------------------------------------------------
// MFMA attention: unchanged from verified baseline.
// ---------------------------------------------------------------------------
__global__ __launch_bounds__(256, 2) void attn_mfma_kernel(
    const float* __restrict__ xyz, const int* __restrict__ knn,
    const float* __restrict__ qv, const float* __restrict__ kv,
    const float* __restrict__ vv, const short* __restrict__ wsw,
    const float* __restrict__ Wd1, const float* __restrict__ bd1,
    const float* __restrict__ bd2, const float* __restrict__ bg1,
    const float* __restrict__ bg2, float* __restrict__ res_ws,
    float* __restrict__ out_attn) {
  const int wv = threadIdx.x >> 6;
  const int lane = threadIdx.x & 63;
  const int g = lane >> 4;   // lane group 0..3
  const int c = lane & 15;   // column-in-tile / A-row
  const int bn = blockIdx.x * 4 + wv;
  const int b = bn >> 12;

  __shared__ __attribute__((aligned(16))) short conv[4][16 * 136];
  __shared__ int sidx[4][16];
  __shared__ float sdelta[4][64];  // [16][4] padded

  if (lane < 16) sidx[wv][lane] = knn[(size_t)bn * 16 + lane];
  __syncthreads();
  if (lane < 48) {
    int k = lane / 3, cc = lane % 3;
    sdelta[wv][k * 4 + cc] = xyz[(size_t)bn * 3 + cc] -
                             xyz[((size_t)(b << 12) + sidx[wv][k]) * 3 + cc];
  }
  __syncthreads();

  // ---- P1 = relu(delta @ Wd1 + bd1) directly as A-fragments ----
  short8 af[4];
  {
    float ddx = sdelta[wv][c * 4 + 0];
    float ddy = sdelta[wv][c * 4 + 1];
    float ddz = sdelta[wv][c * 4 + 2];
#pragma unroll
    for (int s = 0; s < 4; ++s) {
#pragma unroll
      for (int j = 0; j < 8; ++j) {
        int d = s * 32 + g * 8 + j;
        float v = fmaf(ddz, Wd1[256 + d],
                       fmaf(ddy, Wd1[128 + d], fmaf(ddx, Wd1[d], bd1[d])));
        af[s][j] = f2bf(fmaxf(v, 0.f));
      }
    }
  }

  // per-nt scalars
  float qc[8], bd2v[8], bg1v[8], bg2v[8];
#pragma unroll
  for (int nt = 0; nt < 8; ++nt) {
    qc[nt] = qv[(size_t)bn * 128 + nt * 16 + c];
    bd2v[nt] = bd2[nt * 16 + c];
    bg1v[nt] = bg1[nt * 16 + c];
    bg2v[nt] = bg2[nt * 16 + c];
  }

  floatx4 acc[8];

  // ---- stage 1: PE = P1 @ Wd2 + bd2 ----
#pragma unroll
  for (int nt = 0; nt < 8; ++nt) acc[nt] = (floatx4){0.f, 0.f, 0.f, 0.f};
  {
    const short* Wst = wsw;  // stage 0
#pragma unroll
    for (int ks = 0; ks < 4; ++ks) {
#pragma unroll
      for (int nt = 0; nt < 8; ++nt) {
        short8 bf = *reinterpret_cast<const short8*>(
            Wst + ((size_t)(nt * 4 + ks) * 64 + lane) * 8);
        acc[nt] = __builtin_amdgcn_mfma_f32_16x16x32_bf16(af[ks], bf, acc[nt],
                                                          0, 0, 0);
      }
    }
  }

  // ---- H = q - kf + PE ; PE kept fp32 ; H -> LDS (bf16, C-layout) ----
  float PE[8][4];
  int idxr[4];
#pragma unroll
  for (int r = 0; r < 4; ++r) idxr[r] = sidx[wv][g * 4 + r];
#pragma unroll
  for (int nt = 0; nt < 8; ++nt) {
#pragma unroll
    for (int r = 0; r < 4; ++r) {
      float pe = acc[nt][r] + bd2v[nt];
      PE[nt][r] = pe;
      float kvv = kv[((size_t)(b << 12) + idxr[r]) * 128 + nt * 16 + c];
      conv[wv][(g * 4 + r) * 136 + nt * 16 + c] = f2bf(qc[nt] - kvv + pe);
    }
  }
  __syncthreads();
#pragma unroll
  for (int s = 0; s < 4; ++s)
    af[s] = *reinterpret_cast<const short8*>(&conv[wv][c * 136 + s * 32 + g * 8]);
  __syncthreads();

  // ---- stage 2: G = relu(H @ Wg1 + bg1) ----
#pragma unroll
  for (int nt = 0; nt < 8; ++nt) acc[nt] = (floatx4){0.f, 0.f, 0.f, 0.f};
  {
    const short* Wst = wsw + 16384;  // stage 1
#pragma unroll
    for (int ks = 0; ks < 4; ++ks) {
#pragma unroll
      for (int nt = 0; nt < 8; ++nt) {
        short8 bf = *reinterpret_cast<const short8*>(
            Wst + ((size_t)(nt * 4 + ks) * 64 + lane) * 8);
        acc[nt] = __builtin_amdgcn_mfma_f32_16x16x32_bf16(af[ks], bf, acc[nt],
                                                          0, 0, 0);
      }
    }
  }
#pragma unroll
  for (int nt = 0; nt < 8; ++nt) {
#pragma unroll
    for (int r = 0; r < 4; ++r) {
      conv[wv][(g * 4 + r) * 136 + nt * 16 + c] =
          f2bf(fmaxf(acc[nt][r] + bg1v[nt], 0.f));
    }
  }
  __syncthreads();
#pragma unroll
  for (int s = 0; s < 4; ++s)
    af[s] = *reinterpret_cast<const short8*>(&conv[wv][c * 136 + s * 32 + g * 8]);
  __syncthreads();

  // ---- stage 3: logits = G @ Wg2 + bg2 ----
#pragma unroll
  for (int nt = 0; nt < 8; ++nt) acc[nt] = (floatx4){0.f, 0.f, 0.f, 0.f};
  {
    const short* Wst = wsw + 32768;  // stage 2
#pragma unroll
    for (int ks = 0; ks < 4; ++ks) {
#pragma unroll
      for (int nt = 0; nt < 8; ++nt) {
        short8 bf = *reinterpret_cast<const short8*>(
            Wst + ((size_t)(nt * 4 + ks) * 64 + lane) * 8);
        acc[nt] = __builtin_amdgcn_mfma_f32_16x16x32_bf16(af[ks], bf, acc[nt],
                                                          0, 0, 0);
      }
    }
  }

  // ---- softmax over neighbors (rows): 4 local regs + shfl_xor(16,32) ----
  const float inv = 0.0883883476483184f;  // 1/sqrt(128)
  float resv[8];
#pragma unroll
  for (int nt = 0; nt < 8; ++nt) {
    float l0 = (acc[nt][0] + bg2v[nt]) * inv;
    float l1 = (acc[nt][1] + bg2v[nt]) * inv;
    float l2 = (acc[nt][2] + bg2v[nt]) * inv;
    float l3 = (acc[nt][3] + bg2v[nt]) * inv;
    float m4 = fmaxf(fmaxf(l0, l1), fmaxf(l2, l3));
    m4 = fmaxf(m4, __shfl_xor(m4, 16));
    m4 = fmaxf(m4, __shfl_xor(m4, 32));
    float e0 = expf(l0 - m4), e1 = expf(l1 - m4);
    float e2 = expf(l2 - m4), e3 = expf(l3 - m4);
    float s4 = e0 + e1 + e2 + e3;
    s4 += __shfl_xor(s4, 16);
    s4 += __shfl_xor(s4, 32);
    float rs = 1.f / s4;
    float a0 = e0 * rs, a1 = e1 * rs, a2 = e2 * rs, a3 = e3 * rs;
    size_t base = ((size_t)bn * 16 + g * 4) * 128 + nt * 16 + c;
    out_attn[base + 0 * 128] = a0;
    out_attn[base + 1 * 128] = a1;
    out_attn[base + 2 * 128] = a2;
    out_attn[base + 3 * 128] = a3;
    float r = 0.f;
    {
      float v0 = vv[((size_t)(b << 12) + idxr[0]) * 128 + nt * 16 + c];
      float v1 = vv[((size_t)(b << 12) + idxr[1]) * 128 + nt * 16 + c];
      float v2 = vv[((size_t)(b << 12) + idxr[2]) * 128 + nt * 16 + c];
      float v3 = vv[((size_t)(b << 12) + idxr[3]) * 128 + nt * 16 + c];
      r = fmaf(a0, v0 + PE[nt][0], r);
      r = fmaf(a1, v1 + PE[nt][1], r);
      r = fmaf(a2, v2 + PE[nt][2], r);
      r = fmaf(a3, v3 + PE[nt][3], r);
    }
    r += __shfl_xor(r, 16);
    r += __shfl_xor(r, 32);
    resv[nt] = r;
  }
  if (g == 0) {
#pragma unroll
    for (int nt = 0; nt < 8; ++nt)
      res_ws[(size_t)bn * 128 + nt * 16 + c] = resv[nt];
  }
}

// ---------------------------------------------------------------------------
// Epilogue: out_res = res @ W2 + b2 + pre   (16 points/block, mv16)
// ---------------------------------------------------------------------------
__global__ __launch_bounds__(128, 2) void epilogue_kernel(
    const float* __restrict__ res_ws, const float* __restrict__ W2,
    const float* __restrict__ b2, const float* __restrict__ pre,
    float* __restrict__ out_res) {
  const int t = threadIdx.x;
  const int g0 = blockIdx.x * 16;
  __shared__ __attribute__((aligned(16))) float buf[16 * 128];
#pragma unroll
  for (int p = 0; p < 16; ++p)
    buf[p * 128 + t] = res_ws[(size_t)(g0 + p) * 128 + t];
  __syncthreads();
  float acc[16];
  float bb = b2[t];
#pragma unroll
  for (int p = 0; p < 16; ++p)
    acc[p] = bb + pre[(size_t)(g0 + p) * 128 + t];
  mv16(W2 + t, buf, acc);
#pragma unroll
  for (int p = 0; p < 16; ++p)
    out_res[(size_t)(g0 + p) * 128 + t] = acc[p];
}

extern "C" void kernel_launch(void* const* d_in, const int* in_sizes, int n_in,
                              void* d_out, int out_size, void* d_ws,
                              size_t ws_size, hipStream_t stream) {
  const float* xyz = (const float*)d_in[0];
  const float* W0a = (const float*)d_in[1];
  const float* b0a = (const float*)d_in[2];
  const float* W0b = (const float*)d_in[3];
  const float* b0b = (const float*)d_in[4];
  const float* W1 = (const float*)d_in[5];
  const float* b1 = (const float*)d_in[6];
  const float* W2 = (const float*)d_in[7];
  const float* b2 = (const float*)d_in[8];
  const float* Wd1 = (const float*)d_in[9];
  const float* bd1 = (const float*)d_in[10];
  const float* Wd2 = (const float*)d_in[11];
  const float* bd2 = (const float*)d_in[12];
  const float* Wg1 = (const float*)d_in[13];
  const float* bg1 = (const float*)d_in[14];
  const float* Wg2 = (const float*)d_in[15];
  const float* bg2 = (const float*)d_in[16];
  const float* Wq = (const float*)d_in[17];
  const float* Wk = (const float*)d_in[18];
  const float* Wv = (const float*)d_in[19];

  char* ws = (char*)d_ws;
  int* knn = (int*)ws;                                  // 1 MB
  float* pre = (float*)(ws + (1 << 20));                // 8 MB
  float* qv = (float*)(ws + (9 << 20));                 // 8 MB
  float* kv = (float*)(ws + (17 << 20));                // 8 MB
  float* vv = (float*)(ws + (25 << 20));                // 8 MB
  float* res_ws = (float*)(ws + (33 << 20));            // 8 MB
  short* wsw = (short*)(ws + (41 << 20));               // 96 KB bf16 B-frags
  short* wsplit = (short*)(ws + (41 << 20) + (128 << 10));  // 320 KB split frags

  float* out_res = (float*)d_out;
  float* out_attn = out_res + (size_t)BN * DD;

  hipLaunchKernelGGL(swz_kernel, dim3(24), dim3(256), 0, stream, Wd2, Wg1, Wg2,
                     wsw);
  hipLaunchKernelGGL(swz2_kernel, dim3(40), dim3(256), 0, stream, W0b, W1, Wq,
                     Wk, Wv, wsplit);
  hipLaunchKernelGGL(knn_kernel, dim3(4096), dim3(256), 0, stream, xyz, knn);
  hipLaunchKernelGGL(point_mlp_mfma_kernel, dim3(1024), dim3(256), 0, stream,
                     xyz, W0a, b0a, b0b, b1, wsplit, pre, qv, kv, vv);
  hipLaunchKernelGGL(attn_mfma_kernel, dim3(4096), dim3(256), 0, stream, xyz,
                     knn, qv, kv, vv, wsw, Wd1, bd1, bd2, bg1, bg2, res_ws,
                     out_attn);
  hipLaunchKernelGGL(epilogue_kernel, dim3(1024), dim3(128), 0, stream, res_ws,
                     W2, b2, pre, out_res);
}

// Round 2
// 380.989 us; speedup vs baseline: 1.3247x; 1.0659x over previous
//
#include <hip/hip_runtime.h>
#include <math.h>

#define BB 4
#define NN 4096
#define KNNK 16
#define DD 128
#define BN (BB*NN)

typedef __attribute__((ext_vector_type(8))) short short8;   // 8 bf16
typedef __attribute__((ext_vector_type(4))) float floatx4;  // MFMA acc

__device__ __forceinline__ short f2bf(float x) {
  unsigned u = __float_as_uint(x);
  unsigned r = (u + 0x7fffu + ((u >> 16) & 1u)) >> 16;
  return (short)r;
}

__device__ __forceinline__ float bf2f(short h) {
  return __uint_as_float((unsigned)(unsigned short)h << 16);
}

// ---------------------------------------------------------------------------
// Shared split-bf16 GEMM helpers (verified structure from point_mlp round).
// A-frag: af[s][j] = A[row=c][k = s*32 + g*8 + j], split into hi+lo bf16.
// B-frag storage: [mat*2+half][nt][ks][lane][j] with element
//   W[(ks*32 + (lane>>4)*8 + j)*128 + nt*16 + (lane&15)].
// ---------------------------------------------------------------------------
__device__ __forceinline__ void split_from_lds(const float* __restrict__ trans,
                                               int c, int g, short8 ah[4],
                                               short8 al[4]) {
#pragma unroll
  for (int s = 0; s < 4; ++s) {
    const float* p_ = &trans[c * 132 + s * 32 + g * 8];
    float4 u0 = *reinterpret_cast<const float4*>(p_);
    float4 u1 = *reinterpret_cast<const float4*>(p_ + 4);
    float tmp[8] = {u0.x, u0.y, u0.z, u0.w, u1.x, u1.y, u1.z, u1.w};
#pragma unroll
    for (int j = 0; j < 8; ++j) {
      short h_ = f2bf(tmp[j]);
      ah[s][j] = h_;
      al[s][j] = f2bf(tmp[j] - bf2f(h_));
    }
  }
}

__device__ __forceinline__ void split_gemm2(const short* __restrict__ Bh,
                                            int nt0, int lane,
                                            const short8 ah[4],
                                            const short8 al[4], floatx4& acc0,
                                            floatx4& acc1) {
  const short* Bl = Bh + 16384;
#pragma unroll
  for (int ks = 0; ks < 4; ++ks) {
    const size_t o0 = ((size_t)((nt0 + 0) * 4 + ks) * 64 + lane) * 8;
    const size_t o1 = ((size_t)((nt0 + 1) * 4 + ks) * 64 + lane) * 8;
    short8 bh0 = *reinterpret_cast<const short8*>(Bh + o0);
    short8 bl0 = *reinterpret_cast<const short8*>(Bl + o0);
    short8 bh1 = *reinterpret_cast<const short8*>(Bh + o1);
    short8 bl1 = *reinterpret_cast<const short8*>(Bl + o1);
    acc0 = __builtin_amdgcn_mfma_f32_16x16x32_bf16(ah[ks], bh0, acc0, 0, 0, 0);
    acc1 = __builtin_amdgcn_mfma_f32_16x16x32_bf16(ah[ks], bh1, acc1, 0, 0, 0);
    acc0 = __builtin_amdgcn_mfma_f32_16x16x32_bf16(ah[ks], bl0, acc0, 0, 0, 0);
    acc1 = __builtin_amdgcn_mfma_f32_16x16x32_bf16(ah[ks], bl1, acc1, 0, 0, 0);
    acc0 = __builtin_amdgcn_mfma_f32_16x16x32_bf16(al[ks], bh0, acc0, 0, 0, 0);
    acc1 = __builtin_amdgcn_mfma_f32_16x16x32_bf16(al[ks], bh1, acc1, 0, 0, 0);
  }
}

// ---------------------------------------------------------------------------
// KNN v4: one WAVE per query, register-only (verified structure, unchanged).
// ---------------------------------------------------------------------------
__device__ __forceinline__ void ced(double& a, double& b) {
  double mn = fmin(a, b);
  double mx = fmax(a, b);
  a = mn;
  b = mx;
}

__device__ __forceinline__ void dsort16(double v[16]) {
#define CE(i, j) ced(v[i], v[j]);
  CE(0, 1) CE(2, 3) CE(4, 5) CE(6, 7) CE(8, 9) CE(10, 11) CE(12, 13) CE(14, 15)
  CE(0, 2) CE(1, 3) CE(4, 6) CE(5, 7) CE(8, 10) CE(9, 11) CE(12, 14) CE(13, 15)
  CE(1, 2) CE(5, 6) CE(9, 10) CE(13, 14)
  CE(0, 4) CE(1, 5) CE(2, 6) CE(3, 7) CE(8, 12) CE(9, 13) CE(10, 14) CE(11, 15)
  CE(2, 4) CE(3, 5) CE(10, 12) CE(11, 13)
  CE(1, 2) CE(3, 4) CE(5, 6) CE(9, 10) CE(11, 12) CE(13, 14)
  CE(0, 8) CE(1, 9) CE(2, 10) CE(3, 11) CE(4, 12) CE(5, 13) CE(6, 14) CE(7, 15)
  CE(4, 8) CE(5, 9) CE(6, 10) CE(7, 11)
  CE(2, 4) CE(3, 5) CE(6, 8) CE(7, 9) CE(10, 12) CE(11, 13)
  CE(1, 2) CE(3, 4) CE(5, 6) CE(7, 8) CE(9, 10) CE(11, 12) CE(13, 14)
#undef CE
}

// sort a 16-element bitonic sequence ascending
__device__ __forceinline__ void dbitonic16(double m[16]) {
#pragma unroll
  for (int s = 8; s >= 1; s >>= 1) {
#pragma unroll
    for (int i = 0; i < 16; ++i) {
      if ((i & s) == 0) ced(m[i], m[i + s]);
    }
  }
}

__global__ __launch_bounds__(256, 4) void knn_kernel(const float* __restrict__ xyz,
                                                     int* __restrict__ knn) {
  const int wv = threadIdx.x >> 6;
  const int lane = threadIdx.x & 63;
  const int q = blockIdx.x * 4 + wv;
  const int b = q >> 12;
  const int n = q & 4095;
  const float* xb = xyz + (size_t)b * NN * 3;

  const float qx = xb[n * 3 + 0], qy = xb[n * 3 + 1], qz = xb[n * 3 + 2];
  const float qsq = __fadd_rn(__fadd_rn(__fmul_rn(qx, qx), __fmul_rn(qy, qy)),
                              __fmul_rn(qz, qz));

  double top[16];
#pragma unroll
  for (int batch = 0; batch < 4; ++batch) {
    double v[16];
#pragma unroll
    for (int i = 0; i < 16; ++i) {
      const int c = (batch * 16 + i) * 64 + lane;
      float cx = xb[c * 3 + 0], cy = xb[c * 3 + 1], cz = xb[c * 3 + 2];
      float csq = __fadd_rn(__fadd_rn(__fmul_rn(cx, cx), __fmul_rn(cy, cy)),
                            __fmul_rn(cz, cz));
      float dot = __fadd_rn(__fadd_rn(__fmul_rn(qx, cx), __fmul_rn(qy, cy)),
                            __fmul_rn(qz, cz));
      float d = __fadd_rn(__fsub_rn(qsq, __fmul_rn(2.0f, dot)), csq);
      unsigned u = __float_as_uint(d);
      u = (u & 0x80000000u) ? ~u : (u | 0x80000000u);  // monotone float->uint
      unsigned long long key =
          0x3FF0000000000000ULL | (((unsigned long long)u << 12) | (unsigned)c);
      v[i] = __longlong_as_double((long long)key);
    }
    dsort16(v);
    if (batch == 0) {
#pragma unroll
      for (int i = 0; i < 16; ++i) top[i] = v[i];
    } else {
      double m[16];
#pragma unroll
      for (int i = 0; i < 16; ++i)
        m[i] = fmin(top[i], v[15 - i]);  // min(asc, desc) -> bitonic lower half
      dbitonic16(m);
#pragma unroll
      for (int i = 0; i < 16; ++i) top[i] = m[i];
    }
  }

#pragma unroll
  for (int mask = 1; mask <= 32; mask <<= 1) {
    double oth[16];
#pragma unroll
    for (int i = 0; i < 16; ++i) {
      double y = __shfl_xor(top[15 - i], mask);
      oth[i] = fmin(y, top[i]);
    }
    dbitonic16(oth);
#pragma unroll
    for (int i = 0; i < 16; ++i) top[i] = oth[i];
  }

  if (lane == 0) {
    int* outp = knn + (size_t)q * KNNK;
#pragma unroll
    for (int k = 0; k < 16; ++k)
      outp[k] = (int)(__double_as_longlong(top[k]) & 0xFFFLL);
  }
}

// ---------------------------------------------------------------------------
// Combined weight pre-swizzle. First 3*2048 threads: attention-stage bf16
// B-frags (Wd2/Wg1/Wg2) -> wsw. Next 6*2048 threads: split hi/lo bf16 B-frags
// for {W0b, W1, Wq, Wk, Wv, W2} -> wsplit.
// ---------------------------------------------------------------------------
__global__ void swz_all_kernel(const float* __restrict__ Wd2,
                               const float* __restrict__ Wg1,
                               const float* __restrict__ Wg2,
                               const float* __restrict__ W0b,
                               const float* __restrict__ W1,
                               const float* __restrict__ Wq,
                               const float* __restrict__ Wk,
                               const float* __restrict__ Wv,
                               const float* __restrict__ W2,
                               short* __restrict__ wsw,
                               short* __restrict__ wsplit) {
  int t = blockIdx.x * 256 + threadIdx.x;
  if (t < 3 * 2048) {
    int stage = t / 2048;
    int rem = t % 2048;
    int nt = rem / 256;
    int ks = (rem % 256) / 64;
    int lane = rem % 64;
    const float* W = (stage == 0) ? Wd2 : (stage == 1) ? Wg1 : Wg2;
    short8 o;
#pragma unroll
    for (int j = 0; j < 8; ++j) {
      int k = ks * 32 + (lane >> 4) * 8 + j;
      int n = nt * 16 + (lane & 15);
      o[j] = f2bf(W[k * 128 + n]);
    }
    *reinterpret_cast<short8*>(wsw + (size_t)t * 8) = o;
  } else {
    int u = t - 3 * 2048;
    if (u >= 6 * 2048) return;
    int mat = u / 2048;
    int rem = u % 2048;
    int nt = rem / 256;
    int ks = (rem % 256) / 64;
    int lane = rem % 64;
    const float* W = (mat == 0) ? W0b : (mat == 1) ? W1 : (mat == 2) ? Wq
                     : (mat == 3) ? Wk : (mat == 4) ? Wv : W2;
    short8 hi, lo;
#pragma unroll
    for (int j = 0; j < 8; ++j) {
      int k = ks * 32 + (lane >> 4) * 8 + j;
      int n = nt * 16 + (lane & 15);
      float w = W[k * 128 + n];
      short h = f2bf(w);
      hi[j] = h;
      lo[j] = f2bf(w - bf2f(h));
    }
    *reinterpret_cast<short8*>(wsplit + ((size_t)(2 * mat) * 2048 + rem) * 8) = hi;
    *reinterpret_cast<short8*>(wsplit + ((size_t)(2 * mat + 1) * 2048 + rem) * 8) = lo;
  }
}

// ---------------------------------------------------------------------------
// Point-MLP on matrix cores (bf16x2 split). Verified structure, now using
// the shared helpers. Block = 16 points, 4 waves; wave owns 2 N-tiles.
// ---------------------------------------------------------------------------
__global__ __launch_bounds__(256, 4) void point_mlp_mfma_kernel(
    const float* __restrict__ xyz, const float* __restrict__ W0a,
    const float* __restrict__ b0a, const float* __restrict__ b0b,
    const float* __restrict__ b1, const short* __restrict__ wsplit,
    float* __restrict__ pre, float* __restrict__ qv, float* __restrict__ kv,
    float* __restrict__ vv) {
  const int wv = threadIdx.x >> 6;
  const int lane = threadIdx.x & 63;
  const int g = lane >> 4;   // A-frag k-group / D row-group
  const int c = lane & 15;   // A-frag row / D column-in-tile
  const int g0 = blockIdx.x * 16;
  const int nt0 = wv * 2;

  __shared__ __attribute__((aligned(16))) float trans[16 * 132];
  __shared__ float xs[64];
  if (threadIdx.x < 48) {
    int p = threadIdx.x / 3, cc = threadIdx.x % 3;
    xs[p * 4 + cc] = xyz[(size_t)(g0 + p) * 3 + cc];
  }
  __syncthreads();

  short8 ah[4], al[4];
  // ---- fc0a: relu(xyz @ W0a + b0a), computed directly as split A-frags ----
  {
    const float x0 = xs[c * 4 + 0], x1 = xs[c * 4 + 1], x2 = xs[c * 4 + 2];
#pragma unroll
    for (int s = 0; s < 4; ++s) {
#pragma unroll
      for (int j = 0; j < 8; ++j) {
        const int k = s * 32 + g * 8 + j;
        float v = fmaf(x2, W0a[256 + k],
                       fmaf(x1, W0a[128 + k], fmaf(x0, W0a[k], b0a[k])));
        v = fmaxf(v, 0.f);
        const short h = f2bf(v);
        ah[s][j] = h;
        al[s][j] = f2bf(v - bf2f(h));
      }
    }
  }

  floatx4 acc0, acc1;
  const floatx4 zf = (floatx4){0.f, 0.f, 0.f, 0.f};

  // ---- fc0b: pre = A @ W0b + b0b (no relu; pre stored fp32) ----
  acc0 = zf; acc1 = zf;
  split_gemm2(wsplit + 0 * 32768, nt0, lane, ah, al, acc0, acc1);
  {
    const float bb0 = b0b[nt0 * 16 + c];
    const float bb1 = b0b[(nt0 + 1) * 16 + c];
#pragma unroll
    for (int r = 0; r < 4; ++r) {
      const int row = g * 4 + r;
      float v0 = acc0[r] + bb0;
      float v1 = acc1[r] + bb1;
      pre[(size_t)(g0 + row) * 128 + nt0 * 16 + c] = v0;
      pre[(size_t)(g0 + row) * 128 + (nt0 + 1) * 16 + c] = v1;
      trans[row * 132 + nt0 * 16 + c] = v0;
      trans[row * 132 + (nt0 + 1) * 16 + c] = v1;
    }
  }
  __syncthreads();
  split_from_lds(trans, c, g, ah, al);
  __syncthreads();

  // ---- fc1: x = pre @ W1 + b1 ----
  acc0 = zf; acc1 = zf;
  split_gemm2(wsplit + 1 * 32768, nt0, lane, ah, al, acc0, acc1);
  {
    const float bb0 = b1[nt0 * 16 + c];
    const float bb1 = b1[(nt0 + 1) * 16 + c];
#pragma unroll
    for (int r = 0; r < 4; ++r) {
      const int row = g * 4 + r;
      trans[row * 132 + nt0 * 16 + c] = acc0[r] + bb0;
      trans[row * 132 + (nt0 + 1) * 16 + c] = acc1[r] + bb1;
    }
  }
  __syncthreads();
  split_from_lds(trans, c, g, ah, al);
  __syncthreads();

#define GSTORE(dst)                                                            \
  _Pragma("unroll") for (int r = 0; r < 4; ++r) {                              \
    const int row = g0 + g * 4 + r;                                            \
    dst[(size_t)row * 128 + nt0 * 16 + c] = acc0[r];                           \
    dst[(size_t)row * 128 + (nt0 + 1) * 16 + c] = acc1[r];                     \
  }

  // ---- q / k / v projections (no bias) ----
  acc0 = zf; acc1 = zf;
  split_gemm2(wsplit + 2 * 32768, nt0, lane, ah, al, acc0, acc1);
  GSTORE(qv);

  acc0 = zf; acc1 = zf;
  split_gemm2(wsplit + 3 * 32768, nt0, lane, ah, al, acc0, acc1);
  GSTORE(kv);

  acc0 = zf; acc1 = zf;
  split_gemm2(wsplit + 4 * 32768, nt0, lane, ah, al, acc0, acc1);
  GSTORE(vv);

#undef GSTORE
}

// ---------------------------------------------------------------------------
// MFMA attention. Round-2 changes vs verified baseline:
//  - __launch_bounds__(256,4): 4 blocks/CU (VGPR<=128; LDS 17.4KB -> fits)
//  - sidx/sdelta LDS + 2 startup barriers removed: per-lane direct knn/xyz
//    loads (all L2-resident; identical arithmetic)
//  - kv gathered into registers early (kvf), hiding its latency under the
//    Wd1 A-frag VALU build and stage-1 MFMA
// conv round-trip barriers unchanged (verified).
// ---------------------------------------------------------------------------
__global__ __launch_bounds__(256, 4) void attn_mfma_kernel(
    const float* __restrict__ xyz, const int* __restrict__ knn,
    const float* __restrict__ qv, const float* __restrict__ kv,
    const float* __restrict__ vv, const short* __restrict__ wsw,
    const float* __restrict__ Wd1, const float* __restrict__ bd1,
    const float* __restrict__ bd2, const float* __restrict__ bg1,
    const float* __restrict__ bg2, float* __restrict__ res_ws,
    float* __restrict__ out_attn) {
  const int wv = threadIdx.x >> 6;
  const int lane = threadIdx.x & 63;
  const int g = lane >> 4;   // lane group 0..3
  const int c = lane & 15;   // column-in-tile / A-row
  const int bn = blockIdx.x * 4 + wv;
  const int b = bn >> 12;
  const int base_n = b << 12;

  __shared__ __attribute__((aligned(16))) short conv[4][16 * 136];

  // ---- neighbor indices (one 64B line per wave; L2-resident) ----
  const int* knnp = knn + (size_t)bn * 16;
  const int idxn = knnp[c];  // neighbor this lane builds the A-frag row for
  int idxr[4];
#pragma unroll
  for (int r = 0; r < 4; ++r) idxr[r] = knnp[g * 4 + r];

  // ---- kv prefetch into registers (latency hides under VALU + stage 1) ----
  float kvf[8][4];
#pragma unroll
  for (int nt = 0; nt < 8; ++nt)
#pragma unroll
    for (int r = 0; r < 4; ++r)
      kvf[nt][r] = kv[((size_t)(base_n + idxr[r])) * 128 + nt * 16 + c];

  // ---- delta for this lane's neighbor ----
  const float ddx = xyz[(size_t)bn * 3 + 0] - xyz[((size_t)(base_n + idxn)) * 3 + 0];
  const float ddy = xyz[(size_t)bn * 3 + 1] - xyz[((size_t)(base_n + idxn)) * 3 + 1];
  const float ddz = xyz[(size_t)bn * 3 + 2] - xyz[((size_t)(base_n + idxn)) * 3 + 2];

  // ---- P1 = relu(delta @ Wd1 + bd1) directly as A-fragments ----
  short8 af[4];
#pragma unroll
  for (int s = 0; s < 4; ++s) {
#pragma unroll
    for (int j = 0; j < 8; ++j) {
      int d = s * 32 + g * 8 + j;
      float v = fmaf(ddz, Wd1[256 + d],
                     fmaf(ddy, Wd1[128 + d], fmaf(ddx, Wd1[d], bd1[d])));
      af[s][j] = f2bf(fmaxf(v, 0.f));
    }
  }

  // per-nt scalars needed in the H phase
  float qc[8], bd2v[8];
#pragma unroll
  for (int nt = 0; nt < 8; ++nt) {
    qc[nt] = qv[(size_t)bn * 128 + nt * 16 + c];
    bd2v[nt] = bd2[nt * 16 + c];
  }

  floatx4 acc[8];

  // ---- stage 1: PE = P1 @ Wd2 + bd2 ----
#pragma unroll
  for (int nt = 0; nt < 8; ++nt) acc[nt] = (floatx4){0.f, 0.f, 0.f, 0.f};
  {
    const short* Wst = wsw;  // stage 0
#pragma unroll
    for (int ks = 0; ks < 4; ++ks) {
#pragma unroll
      for (int nt = 0; nt < 8; ++nt) {
        short8 bf = *reinterpret_cast<const short8*>(
            Wst + ((size_t)(nt * 4 + ks) * 64 + lane) * 8);
        acc[nt] = __builtin_amdgcn_mfma_f32_16x16x32_bf16(af[ks], bf, acc[nt],
                                                          0, 0, 0);
      }
    }
  }

  // ---- H = q - kf + PE ; PE kept fp32 ; H -> LDS (bf16, C-layout) ----
  float PE[8][4];
#pragma unroll
  for (int nt = 0; nt < 8; ++nt) {
#pragma unroll
    for (int r = 0; r < 4; ++r) {
      float pe = acc[nt][r] + bd2v[nt];
      PE[nt][r] = pe;
      conv[wv][(g * 4 + r) * 136 + nt * 16 + c] =
          f2bf(qc[nt] - kvf[nt][r] + pe);
    }
  }
  __syncthreads();
#pragma unroll
  for (int s = 0; s < 4; ++s)
    af[s] = *reinterpret_cast<const short8*>(&conv[wv][c * 136 + s * 32 + g * 8]);
  __syncthreads();

  // ---- stage 2: G = relu(H @ Wg1 + bg1) ----
#pragma unroll
  for (int nt = 0; nt < 8; ++nt) acc[nt] = (floatx4){0.f, 0.f, 0.f, 0.f};
  {
    const short* Wst = wsw + 16384;  // stage 1
#pragma unroll
    for (int ks = 0; ks < 4; ++ks) {
#pragma unroll
      for (int nt = 0; nt < 8; ++nt) {
        short8 bf = *reinterpret_cast<const short8*>(
            Wst + ((size_t)(nt * 4 + ks) * 64 + lane) * 8);
        acc[nt] = __builtin_amdgcn_mfma_f32_16x16x32_bf16(af[ks], bf, acc[nt],
                                                          0, 0, 0);
      }
    }
  }
#pragma unroll
  for (int nt = 0; nt < 8; ++nt) {
    const float bg1v = bg1[nt * 16 + c];
#pragma unroll
    for (int r = 0; r < 4; ++r) {
      conv[wv][(g * 4 + r) * 136 + nt * 16 + c] =
          f2bf(fmaxf(acc[nt][r] + bg1v, 0.f));
    }
  }
  __syncthreads();
#pragma unroll
  for (int s = 0; s < 4; ++s)
    af[s] = *reinterpret_cast<const short8*>(&conv[wv][c * 136 + s * 32 + g * 8]);
  __syncthreads();

  // ---- stage 3: logits = G @ Wg2 + bg2 ----
#pragma unroll
  for (int nt = 0; nt < 8; ++nt) acc[nt] = (floatx4){0.f, 0.f, 0.f, 0.f};
  {
    const short* Wst = wsw + 32768;  // stage 2
#pragma unroll
    for (int ks = 0; ks < 4; ++ks) {
#pragma unroll
      for (int nt = 0; nt < 8; ++nt) {
        short8 bf = *reinterpret_cast<const short8*>(
            Wst + ((size_t)(nt * 4 + ks) * 64 + lane) * 8);
        acc[nt] = __builtin_amdgcn_mfma_f32_16x16x32_bf16(af[ks], bf, acc[nt],
                                                          0, 0, 0);
      }
    }
  }

  // ---- softmax over neighbors (rows): 4 local regs + shfl_xor(16,32) ----
  const float inv = 0.0883883476483184f;  // 1/sqrt(128)
  float resv[8];
#pragma unroll
  for (int nt = 0; nt < 8; ++nt) {
    const float bg2v = bg2[nt * 16 + c];
    float l0 = (acc[nt][0] + bg2v) * inv;
    float l1 = (acc[nt][1] + bg2v) * inv;
    float l2 = (acc[nt][2] + bg2v) * inv;
    float l3 = (acc[nt][3] + bg2v) * inv;
    float m4 = fmaxf(fmaxf(l0, l1), fmaxf(l2, l3));
    m4 = fmaxf(m4, __shfl_xor(m4, 16));
    m4 = fmaxf(m4, __shfl_xor(m4, 32));
    float e0 = expf(l0 - m4), e1 = expf(l1 - m4);
    float e2 = expf(l2 - m4), e3 = expf(l3 - m4);
    float s4 = e0 + e1 + e2 + e3;
    s4 += __shfl_xor(s4, 16);
    s4 += __shfl_xor(s4, 32);
    float rs = 1.f / s4;
    float a0 = e0 * rs, a1 = e1 * rs, a2 = e2 * rs, a3 = e3 * rs;
    size_t base = ((size_t)bn * 16 + g * 4) * 128 + nt * 16 + c;
    out_attn[base + 0 * 128] = a0;
    out_attn[base + 1 * 128] = a1;
    out_attn[base + 2 * 128] = a2;
    out_attn[base + 3 * 128] = a3;
    float r = 0.f;
    {
      float v0 = vv[((size_t)(base_n + idxr[0])) * 128 + nt * 16 + c];
      float v1 = vv[((size_t)(base_n + idxr[1])) * 128 + nt * 16 + c];
      float v2 = vv[((size_t)(base_n + idxr[2])) * 128 + nt * 16 + c];
      float v3 = vv[((size_t)(base_n + idxr[3])) * 128 + nt * 16 + c];
      r = fmaf(a0, v0 + PE[nt][0], r);
      r = fmaf(a1, v1 + PE[nt][1], r);
      r = fmaf(a2, v2 + PE[nt][2], r);
      r = fmaf(a3, v3 + PE[nt][3], r);
    }
    r += __shfl_xor(r, 16);
    r += __shfl_xor(r, 32);
    resv[nt] = r;
  }
  if (g == 0) {
#pragma unroll
    for (int nt = 0; nt < 8; ++nt)
      res_ws[(size_t)bn * 128 + nt * 16 + c] = resv[nt];
  }
}

// ---------------------------------------------------------------------------
// Epilogue on matrix cores: out_res = res @ W2 + b2 + pre.
// 16 points/block, 4 waves, wave owns 2 N-tiles; W2 split frags = mat 5.
// ---------------------------------------------------------------------------
__global__ __launch_bounds__(256, 4) void epilogue_mfma_kernel(
    const float* __restrict__ res_ws, const short* __restrict__ wsplit,
    const float* __restrict__ b2, const float* __restrict__ pre,
    float* __restrict__ out_res) {
  const int wv = threadIdx.x >> 6;
  const int lane = threadIdx.x & 63;
  const int g = lane >> 4;
  const int c = lane & 15;
  const int g0 = blockIdx.x * 16;
  const int nt0 = wv * 2;

  __shared__ __attribute__((aligned(16))) float trans[16 * 132];

  // coalesced load of the 16x128 res block into LDS (float4, 2 per thread)
#pragma unroll
  for (int i = 0; i < 2; ++i) {
    int idx4 = threadIdx.x + i * 256;  // 0..511 float4s
    int row = idx4 >> 5;
    int col4 = idx4 & 31;
    float4 v = *reinterpret_cast<const float4*>(
        res_ws + (size_t)(g0 + row) * 128 + col4 * 4);
    *reinterpret_cast<float4*>(&trans[row * 132 + col4 * 4]) = v;
  }
  __syncthreads();

  short8 ah[4], al[4];
  split_from_lds(trans, c, g, ah, al);

  // prefetch pre + b2 (overlaps the MFMAs)
  float prv0[4], prv1[4];
  const float bb0 = b2[nt0 * 16 + c];
  const float bb1 = b2[(nt0 + 1) * 16 + c];
#pragma unroll
  for (int r = 0; r < 4; ++r) {
    prv0[r] = pre[(size_t)(g0 + g * 4 + r) * 128 + nt0 * 16 + c];
    prv1[r] = pre[(size_t)(g0 + g * 4 + r) * 128 + (nt0 + 1) * 16 + c];
  }

  floatx4 acc0 = (floatx4){0.f, 0.f, 0.f, 0.f};
  floatx4 acc1 = (floatx4){0.f, 0.f, 0.f, 0.f};
  split_gemm2(wsplit + 5 * 32768, nt0, lane, ah, al, acc0, acc1);

#pragma unroll
  for (int r = 0; r < 4; ++r) {
    const int row = g0 + g * 4 + r;
    out_res[(size_t)row * 128 + nt0 * 16 + c] = acc0[r] + bb0 + prv0[r];
    out_res[(size_t)row * 128 + (nt0 + 1) * 16 + c] = acc1[r] + bb1 + prv1[r];
  }
}

extern "C" void kernel_launch(void* const* d_in, const int* in_sizes, int n_in,
                              void* d_out, int out_size, void* d_ws,
                              size_t ws_size, hipStream_t stream) {
  const float* xyz = (const float*)d_in[0];
  const float* W0a = (const float*)d_in[1];
  const float* b0a = (const float*)d_in[2];
  const float* W0b = (const float*)d_in[3];
  const float* b0b = (const float*)d_in[4];
  const float* W1 = (const float*)d_in[5];
  const float* b1 = (const float*)d_in[6];
  const float* W2 = (const float*)d_in[7];
  const float* b2 = (const float*)d_in[8];
  const float* Wd1 = (const float*)d_in[9];
  const float* bd1 = (const float*)d_in[10];
  const float* Wd2 = (const float*)d_in[11];
  const float* bd2 = (const float*)d_in[12];
  const float* Wg1 = (const float*)d_in[13];
  const float* bg1 = (const float*)d_in[14];
  const float* Wg2 = (const float*)d_in[15];
  const float* bg2 = (const float*)d_in[16];
  const float* Wq = (const float*)d_in[17];
  const float* Wk = (const float*)d_in[18];
  const float* Wv = (const float*)d_in[19];

  char* ws = (char*)d_ws;
  int* knn = (int*)ws;                                  // 1 MB
  float* pre = (float*)(ws + (1 << 20));                // 8 MB
  float* qv = (float*)(ws + (9 << 20));                 // 8 MB
  float* kv = (float*)(ws + (17 << 20));                // 8 MB
  float* vv = (float*)(ws + (25 << 20));                // 8 MB
  float* res_ws = (float*)(ws + (33 << 20));            // 8 MB
  short* wsw = (short*)(ws + (41 << 20));               // 96 KB bf16 B-frags
  short* wsplit = (short*)(ws + (41 << 20) + (128 << 10));  // 384 KB split frags

  float* out_res = (float*)d_out;
  float* out_attn = out_res + (size_t)BN * DD;

  hipLaunchKernelGGL(swz_all_kernel, dim3(72), dim3(256), 0, stream, Wd2, Wg1,
                     Wg2, W0b, W1, Wq, Wk, Wv, W2, wsw, wsplit);
  hipLaunchKernelGGL(knn_kernel, dim3(4096), dim3(256), 0, stream, xyz, knn);
  hipLaunchKernelGGL(point_mlp_mfma_kernel, dim3(1024), dim3(256), 0, stream,
                     xyz, W0a, b0a, b0b, b1, wsplit, pre, qv, kv, vv);
  hipLaunchKernelGGL(attn_mfma_kernel, dim3(4096), dim3(256), 0, stream, xyz,
                     knn, qv, kv, vv, wsw, Wd1, bd1, bd2, bg1, bg2, res_ws,
                     out_attn);
  hipLaunchKernelGGL(epilogue_mfma_kernel, dim3(1024), dim3(256), 0, stream,
                     res_ws, wsplit, b2, pre, out_res);
}

// Round 3
// 373.311 us; speedup vs baseline: 1.3519x; 1.0206x over previous
//
#include <hip/hip_runtime.h>
#include <math.h>

#define BB 4
#define NN 4096
#define KNNK 16
#define DD 128
#define BN (BB*NN)

typedef __attribute__((ext_vector_type(8))) short short8;   // 8 bf16
typedef __attribute__((ext_vector_type(4))) float floatx4;  // MFMA acc

__device__ __forceinline__ short f2bf(float x) {
  unsigned u = __float_as_uint(x);
  unsigned r = (u + 0x7fffu + ((u >> 16) & 1u)) >> 16;
  return (short)r;
}

__device__ __forceinline__ float bf2f(short h) {
  return __uint_as_float((unsigned)(unsigned short)h << 16);
}

// Per-wave LDS fence: conv[] is wave-private, so a full block barrier is
// unnecessary; DS ops of one wave process in order, the waitcnt guarantees
// the writes have landed before the reads issue, and the "memory" clobber
// stops the compiler from moving the C++ ds_read/ds_write across it.
#define LDSFENCE() asm volatile("s_waitcnt lgkmcnt(0)" ::: "memory")

// ---------------------------------------------------------------------------
// Shared split-bf16 GEMM helpers (verified structure).
// A-frag: af[s][j] = A[row=c][k = s*32 + g*8 + j], split into hi+lo bf16.
// B-frag storage: [mat*2+half][nt][ks][lane][j] with element
//   W[(ks*32 + (lane>>4)*8 + j)*128 + nt*16 + (lane&15)].
// ---------------------------------------------------------------------------
__device__ __forceinline__ void split_from_lds(const float* __restrict__ trans,
                                               int c, int g, short8 ah[4],
                                               short8 al[4]) {
#pragma unroll
  for (int s = 0; s < 4; ++s) {
    const float* p_ = &trans[c * 132 + s * 32 + g * 8];
    float4 u0 = *reinterpret_cast<const float4*>(p_);
    float4 u1 = *reinterpret_cast<const float4*>(p_ + 4);
    float tmp[8] = {u0.x, u0.y, u0.z, u0.w, u1.x, u1.y, u1.z, u1.w};
#pragma unroll
    for (int j = 0; j < 8; ++j) {
      short h_ = f2bf(tmp[j]);
      ah[s][j] = h_;
      al[s][j] = f2bf(tmp[j] - bf2f(h_));
    }
  }
}

__device__ __forceinline__ void split_gemm2(const short* __restrict__ Bh,
                                            int nt0, int lane,
                                            const short8 ah[4],
                                            const short8 al[4], floatx4& acc0,
                                            floatx4& acc1) {
  const short* Bl = Bh + 16384;
#pragma unroll
  for (int ks = 0; ks < 4; ++ks) {
    const size_t o0 = ((size_t)((nt0 + 0) * 4 + ks) * 64 + lane) * 8;
    const size_t o1 = ((size_t)((nt0 + 1) * 4 + ks) * 64 + lane) * 8;
    short8 bh0 = *reinterpret_cast<const short8*>(Bh + o0);
    short8 bl0 = *reinterpret_cast<const short8*>(Bl + o0);
    short8 bh1 = *reinterpret_cast<const short8*>(Bh + o1);
    short8 bl1 = *reinterpret_cast<const short8*>(Bl + o1);
    acc0 = __builtin_amdgcn_mfma_f32_16x16x32_bf16(ah[ks], bh0, acc0, 0, 0, 0);
    acc1 = __builtin_amdgcn_mfma_f32_16x16x32_bf16(ah[ks], bh1, acc1, 0, 0, 0);
    acc0 = __builtin_amdgcn_mfma_f32_16x16x32_bf16(ah[ks], bl0, acc0, 0, 0, 0);
    acc1 = __builtin_amdgcn_mfma_f32_16x16x32_bf16(ah[ks], bl1, acc1, 0, 0, 0);
    acc0 = __builtin_amdgcn_mfma_f32_16x16x32_bf16(al[ks], bh0, acc0, 0, 0, 0);
    acc1 = __builtin_amdgcn_mfma_f32_16x16x32_bf16(al[ks], bh1, acc1, 0, 0, 0);
  }
}

// ---------------------------------------------------------------------------
// KNN v4: one WAVE per query, register-only (verified structure, unchanged).
// ---------------------------------------------------------------------------
__device__ __forceinline__ void ced(double& a, double& b) {
  double mn = fmin(a, b);
  double mx = fmax(a, b);
  a = mn;
  b = mx;
}

__device__ __forceinline__ void dsort16(double v[16]) {
#define CE(i, j) ced(v[i], v[j]);
  CE(0, 1) CE(2, 3) CE(4, 5) CE(6, 7) CE(8, 9) CE(10, 11) CE(12, 13) CE(14, 15)
  CE(0, 2) CE(1, 3) CE(4, 6) CE(5, 7) CE(8, 10) CE(9, 11) CE(12, 14) CE(13, 15)
  CE(1, 2) CE(5, 6) CE(9, 10) CE(13, 14)
  CE(0, 4) CE(1, 5) CE(2, 6) CE(3, 7) CE(8, 12) CE(9, 13) CE(10, 14) CE(11, 15)
  CE(2, 4) CE(3, 5) CE(10, 12) CE(11, 13)
  CE(1, 2) CE(3, 4) CE(5, 6) CE(9, 10) CE(11, 12) CE(13, 14)
  CE(0, 8) CE(1, 9) CE(2, 10) CE(3, 11) CE(4, 12) CE(5, 13) CE(6, 14) CE(7, 15)
  CE(4, 8) CE(5, 9) CE(6, 10) CE(7, 11)
  CE(2, 4) CE(3, 5) CE(6, 8) CE(7, 9) CE(10, 12) CE(11, 13)
  CE(1, 2) CE(3, 4) CE(5, 6) CE(7, 8) CE(9, 10) CE(11, 12) CE(13, 14)
#undef CE
}

// sort a 16-element bitonic sequence ascending
__device__ __forceinline__ void dbitonic16(double m[16]) {
#pragma unroll
  for (int s = 8; s >= 1; s >>= 1) {
#pragma unroll
    for (int i = 0; i < 16; ++i) {
      if ((i & s) == 0) ced(m[i], m[i + s]);
    }
  }
}

__global__ __launch_bounds__(256, 4) void knn_kernel(const float* __restrict__ xyz,
                                                     int* __restrict__ knn) {
  const int wv = threadIdx.x >> 6;
  const int lane = threadIdx.x & 63;
  const int q = blockIdx.x * 4 + wv;
  const int b = q >> 12;
  const int n = q & 4095;
  const float* xb = xyz + (size_t)b * NN * 3;

  const float qx = xb[n * 3 + 0], qy = xb[n * 3 + 1], qz = xb[n * 3 + 2];
  const float qsq = __fadd_rn(__fadd_rn(__fmul_rn(qx, qx), __fmul_rn(qy, qy)),
                              __fmul_rn(qz, qz));

  double top[16];
#pragma unroll
  for (int batch = 0; batch < 4; ++batch) {
    double v[16];
#pragma unroll
    for (int i = 0; i < 16; ++i) {
      const int c = (batch * 16 + i) * 64 + lane;
      float cx = xb[c * 3 + 0], cy = xb[c * 3 + 1], cz = xb[c * 3 + 2];
      float csq = __fadd_rn(__fadd_rn(__fmul_rn(cx, cx), __fmul_rn(cy, cy)),
                            __fmul_rn(cz, cz));
      float dot = __fadd_rn(__fadd_rn(__fmul_rn(qx, cx), __fmul_rn(qy, cy)),
                            __fmul_rn(qz, cz));
      float d = __fadd_rn(__fsub_rn(qsq, __fmul_rn(2.0f, dot)), csq);
      unsigned u = __float_as_uint(d);
      u = (u & 0x80000000u) ? ~u : (u | 0x80000000u);  // monotone float->uint
      unsigned long long key =
          0x3FF0000000000000ULL | (((unsigned long long)u << 12) | (unsigned)c);
      v[i] = __longlong_as_double((long long)key);
    }
    dsort16(v);
    if (batch == 0) {
#pragma unroll
      for (int i = 0; i < 16; ++i) top[i] = v[i];
    } else {
      double m[16];
#pragma unroll
      for (int i = 0; i < 16; ++i)
        m[i] = fmin(top[i], v[15 - i]);  // min(asc, desc) -> bitonic lower half
      dbitonic16(m);
#pragma unroll
      for (int i = 0; i < 16; ++i) top[i] = m[i];
    }
  }

#pragma unroll
  for (int mask = 1; mask <= 32; mask <<= 1) {
    double oth[16];
#pragma unroll
    for (int i = 0; i < 16; ++i) {
      double y = __shfl_xor(top[15 - i], mask);
      oth[i] = fmin(y, top[i]);
    }
    dbitonic16(oth);
#pragma unroll
    for (int i = 0; i < 16; ++i) top[i] = oth[i];
  }

  if (lane == 0) {
    int* outp = knn + (size_t)q * KNNK;
#pragma unroll
    for (int k = 0; k < 16; ++k)
      outp[k] = (int)(__double_as_longlong(top[k]) & 0xFFFLL);
  }
}

// ---------------------------------------------------------------------------
// Combined weight pre-swizzle. First 3*2048 threads: attention-stage bf16
// B-frags (Wd2/Wg1/Wg2) -> wsw. Next 6*2048 threads: split hi/lo bf16 B-frags
// for {W0b, W1, Wq, Wk, Wv, W2} -> wsplit.
// ---------------------------------------------------------------------------
__global__ void swz_all_kernel(const float* __restrict__ Wd2,
                               const float* __restrict__ Wg1,
                               const float* __restrict__ Wg2,
                               const float* __restrict__ W0b,
                               const float* __restrict__ W1,
                               const float* __restrict__ Wq,
                               const float* __restrict__ Wk,
                               const float* __restrict__ Wv,
                               const float* __restrict__ W2,
                               short* __restrict__ wsw,
                               short* __restrict__ wsplit) {
  int t = blockIdx.x * 256 + threadIdx.x;
  if (t < 3 * 2048) {
    int stage = t / 2048;
    int rem = t % 2048;
    int nt = rem / 256;
    int ks = (rem % 256) / 64;
    int lane = rem % 64;
    const float* W = (stage == 0) ? Wd2 : (stage == 1) ? Wg1 : Wg2;
    short8 o;
#pragma unroll
    for (int j = 0; j < 8; ++j) {
      int k = ks * 32 + (lane >> 4) * 8 + j;
      int n = nt * 16 + (lane & 15);
      o[j] = f2bf(W[k * 128 + n]);
    }
    *reinterpret_cast<short8*>(wsw + (size_t)t * 8) = o;
  } else {
    int u = t - 3 * 2048;
    if (u >= 6 * 2048) return;
    int mat = u / 2048;
    int rem = u % 2048;
    int nt = rem / 256;
    int ks = (rem % 256) / 64;
    int lane = rem % 64;
    const float* W = (mat == 0) ? W0b : (mat == 1) ? W1 : (mat == 2) ? Wq
                     : (mat == 3) ? Wk : (mat == 4) ? Wv : W2;
    short8 hi, lo;
#pragma unroll
    for (int j = 0; j < 8; ++j) {
      int k = ks * 32 + (lane >> 4) * 8 + j;
      int n = nt * 16 + (lane & 15);
      float w = W[k * 128 + n];
      short h = f2bf(w);
      hi[j] = h;
      lo[j] = f2bf(w - bf2f(h));
    }
    *reinterpret_cast<short8*>(wsplit + ((size_t)(2 * mat) * 2048 + rem) * 8) = hi;
    *reinterpret_cast<short8*>(wsplit + ((size_t)(2 * mat + 1) * 2048 + rem) * 8) = lo;
  }
}

// ---------------------------------------------------------------------------
// Point-MLP on matrix cores (bf16x2 split). Verified structure (unchanged).
// ---------------------------------------------------------------------------
__global__ __launch_bounds__(256, 4) void point_mlp_mfma_kernel(
    const float* __restrict__ xyz, const float* __restrict__ W0a,
    const float* __restrict__ b0a, const float* __restrict__ b0b,
    const float* __restrict__ b1, const short* __restrict__ wsplit,
    float* __restrict__ pre, float* __restrict__ qv, float* __restrict__ kv,
    float* __restrict__ vv) {
  const int wv = threadIdx.x >> 6;
  const int lane = threadIdx.x & 63;
  const int g = lane >> 4;   // A-frag k-group / D row-group
  const int c = lane & 15;   // A-frag row / D column-in-tile
  const int g0 = blockIdx.x * 16;
  const int nt0 = wv * 2;

  __shared__ __attribute__((aligned(16))) float trans[16 * 132];
  __shared__ float xs[64];
  if (threadIdx.x < 48) {
    int p = threadIdx.x / 3, cc = threadIdx.x % 3;
    xs[p * 4 + cc] = xyz[(size_t)(g0 + p) * 3 + cc];
  }
  __syncthreads();

  short8 ah[4], al[4];
  // ---- fc0a: relu(xyz @ W0a + b0a), computed directly as split A-frags ----
  {
    const float x0 = xs[c * 4 + 0], x1 = xs[c * 4 + 1], x2 = xs[c * 4 + 2];
#pragma unroll
    for (int s = 0; s < 4; ++s) {
#pragma unroll
      for (int j = 0; j < 8; ++j) {
        const int k = s * 32 + g * 8 + j;
        float v = fmaf(x2, W0a[256 + k],
                       fmaf(x1, W0a[128 + k], fmaf(x0, W0a[k], b0a[k])));
        v = fmaxf(v, 0.f);
        const short h = f2bf(v);
        ah[s][j] = h;
        al[s][j] = f2bf(v - bf2f(h));
      }
    }
  }

  floatx4 acc0, acc1;
  const floatx4 zf = (floatx4){0.f, 0.f, 0.f, 0.f};

  // ---- fc0b: pre = A @ W0b + b0b (no relu; pre stored fp32) ----
  acc0 = zf; acc1 = zf;
  split_gemm2(wsplit + 0 * 32768, nt0, lane, ah, al, acc0, acc1);
  {
    const float bb0 = b0b[nt0 * 16 + c];
    const float bb1 = b0b[(nt0 + 1) * 16 + c];
#pragma unroll
    for (int r = 0; r < 4; ++r) {
      const int row = g * 4 + r;
      float v0 = acc0[r] + bb0;
      float v1 = acc1[r] + bb1;
      pre[(size_t)(g0 + row) * 128 + nt0 * 16 + c] = v0;
      pre[(size_t)(g0 + row) * 128 + (nt0 + 1) * 16 + c] = v1;
      trans[row * 132 + nt0 * 16 + c] = v0;
      trans[row * 132 + (nt0 + 1) * 16 + c] = v1;
    }
  }
  __syncthreads();
  split_from_lds(trans, c, g, ah, al);
  __syncthreads();

  // ---- fc1: x = pre @ W1 + b1 ----
  acc0 = zf; acc1 = zf;
  split_gemm2(wsplit + 1 * 32768, nt0, lane, ah, al, acc0, acc1);
  {
    const float bb0 = b1[nt0 * 16 + c];
    const float bb1 = b1[(nt0 + 1) * 16 + c];
#pragma unroll
    for (int r = 0; r < 4; ++r) {
      const int row = g * 4 + r;
      trans[row * 132 + nt0 * 16 + c] = acc0[r] + bb0;
      trans[row * 132 + (nt0 + 1) * 16 + c] = acc1[r] + bb1;
    }
  }
  __syncthreads();
  split_from_lds(trans, c, g, ah, al);
  __syncthreads();

#define GSTORE(dst)                                                            \
  _Pragma("unroll") for (int r = 0; r < 4; ++r) {                              \
    const int row = g0 + g * 4 + r;                                            \
    dst[(size_t)row * 128 + nt0 * 16 + c] = acc0[r];                           \
    dst[(size_t)row * 128 + (nt0 + 1) * 16 + c] = acc1[r];                     \
  }

  // ---- q / k / v projections (no bias) ----
  acc0 = zf; acc1 = zf;
  split_gemm2(wsplit + 2 * 32768, nt0, lane, ah, al, acc0, acc1);
  GSTORE(qv);

  acc0 = zf; acc1 = zf;
  split_gemm2(wsplit + 3 * 32768, nt0, lane, ah, al, acc0, acc1);
  GSTORE(kv);

  acc0 = zf; acc1 = zf;
  split_gemm2(wsplit + 4 * 32768, nt0, lane, ah, al, acc0, acc1);
  GSTORE(vv);

#undef GSTORE
}

// ---------------------------------------------------------------------------
// MFMA attention. Round-3 changes:
//  - NO __syncthreads at all: conv[] is wave-private, per-wave lgkmcnt(0)
//    fences replace the 4 barriers (waves decouple; no lockstep on gathers)
//  - B-frag loads grouped 4-at-a-time ahead of their 4 MFMAs
//  - stage 3 + softmax split into two 4-nt halves; vv gathered per half
//    before the half's MFMAs (latency hidden under MFMA + B-frag loads)
// ---------------------------------------------------------------------------
__global__ __launch_bounds__(256, 4) void attn_mfma_kernel(
    const float* __restrict__ xyz, const int* __restrict__ knn,
    const float* __restrict__ qv, const float* __restrict__ kv,
    const float* __restrict__ vv, const short* __restrict__ wsw,
    const float* __restrict__ Wd1, const float* __restrict__ bd1,
    const float* __restrict__ bd2, const float* __restrict__ bg1,
    const float* __restrict__ bg2, float* __restrict__ res_ws,
    float* __restrict__ out_attn) {
  const int wv = threadIdx.x >> 6;
  const int lane = threadIdx.x & 63;
  const int g = lane >> 4;   // lane group 0..3
  const int c = lane & 15;   // column-in-tile / A-row
  const int bn = blockIdx.x * 4 + wv;
  const int b = bn >> 12;
  const int base_n = b << 12;

  __shared__ __attribute__((aligned(16))) short conv[4][16 * 136];

  // ---- neighbor indices (one 64B line per wave; L2-resident) ----
  const int* knnp = knn + (size_t)bn * 16;
  const int idxn = knnp[c];  // neighbor this lane builds the A-frag row for
  int idxr[4];
#pragma unroll
  for (int r = 0; r < 4; ++r) idxr[r] = knnp[g * 4 + r];

  // ---- kv prefetch into registers (latency hides under VALU + stage 1) ----
  float kvf[8][4];
#pragma unroll
  for (int nt = 0; nt < 8; ++nt)
#pragma unroll
    for (int r = 0; r < 4; ++r)
      kvf[nt][r] = kv[((size_t)(base_n + idxr[r])) * 128 + nt * 16 + c];

  // ---- delta for this lane's neighbor ----
  const float ddx = xyz[(size_t)bn * 3 + 0] - xyz[((size_t)(base_n + idxn)) * 3 + 0];
  const float ddy = xyz[(size_t)bn * 3 + 1] - xyz[((size_t)(base_n + idxn)) * 3 + 1];
  const float ddz = xyz[(size_t)bn * 3 + 2] - xyz[((size_t)(base_n + idxn)) * 3 + 2];

  // ---- P1 = relu(delta @ Wd1 + bd1) directly as A-fragments ----
  short8 af[4];
#pragma unroll
  for (int s = 0; s < 4; ++s) {
#pragma unroll
    for (int j = 0; j < 8; ++j) {
      int d = s * 32 + g * 8 + j;
      float v = fmaf(ddz, Wd1[256 + d],
                     fmaf(ddy, Wd1[128 + d], fmaf(ddx, Wd1[d], bd1[d])));
      af[s][j] = f2bf(fmaxf(v, 0.f));
    }
  }

  // per-nt scalars needed in the H phase
  float qc[8], bd2v[8];
#pragma unroll
  for (int nt = 0; nt < 8; ++nt) {
    qc[nt] = qv[(size_t)bn * 128 + nt * 16 + c];
    bd2v[nt] = bd2[nt * 16 + c];
  }

  floatx4 acc[8];

// grouped-load stage GEMM over all 8 nt tiles
#define STAGE_GEMM(WOFF)                                                       \
  {                                                                            \
    const short* Wst = wsw + (WOFF);                                           \
    _Pragma("unroll") for (int ks = 0; ks < 4; ++ks) {                         \
      _Pragma("unroll") for (int h2 = 0; h2 < 2; ++h2) {                       \
        short8 bfr[4];                                                         \
        _Pragma("unroll") for (int i = 0; i < 4; ++i)                          \
          bfr[i] = *reinterpret_cast<const short8*>(                           \
              Wst + ((size_t)((h2 * 4 + i) * 4 + ks) * 64 + lane) * 8);        \
        _Pragma("unroll") for (int i = 0; i < 4; ++i)                          \
          acc[h2 * 4 + i] = __builtin_amdgcn_mfma_f32_16x16x32_bf16(           \
              af[ks], bfr[i], acc[h2 * 4 + i], 0, 0, 0);                       \
      }                                                                        \
    }                                                                          \
  }

  // ---- stage 1: PE = P1 @ Wd2 + bd2 ----
#pragma unroll
  for (int nt = 0; nt < 8; ++nt) acc[nt] = (floatx4){0.f, 0.f, 0.f, 0.f};
  STAGE_GEMM(0);

  // ---- H = q - kf + PE ; PE kept fp32 ; H -> LDS (bf16, C-layout) ----
  float PE[8][4];
#pragma unroll
  for (int nt = 0; nt < 8; ++nt) {
#pragma unroll
    for (int r = 0; r < 4; ++r) {
      float pe = acc[nt][r] + bd2v[nt];
      PE[nt][r] = pe;
      conv[wv][(g * 4 + r) * 136 + nt * 16 + c] =
          f2bf(qc[nt] - kvf[nt][r] + pe);
    }
  }
  LDSFENCE();
#pragma unroll
  for (int s = 0; s < 4; ++s)
    af[s] = *reinterpret_cast<const short8*>(&conv[wv][c * 136 + s * 32 + g * 8]);

  // ---- stage 2: G = relu(H @ Wg1 + bg1) ----
#pragma unroll
  for (int nt = 0; nt < 8; ++nt) acc[nt] = (floatx4){0.f, 0.f, 0.f, 0.f};
  STAGE_GEMM(16384);
#pragma unroll
  for (int nt = 0; nt < 8; ++nt) {
    const float bg1v = bg1[nt * 16 + c];
#pragma unroll
    for (int r = 0; r < 4; ++r) {
      conv[wv][(g * 4 + r) * 136 + nt * 16 + c] =
          f2bf(fmaxf(acc[nt][r] + bg1v, 0.f));
    }
  }
  LDSFENCE();
#pragma unroll
  for (int s = 0; s < 4; ++s)
    af[s] = *reinterpret_cast<const short8*>(&conv[wv][c * 136 + s * 32 + g * 8]);

  // ---- stage 3 + softmax, two 4-nt halves; vv prefetched per half ----
  const float inv = 0.0883883476483184f;  // 1/sqrt(128)
  float resv[8];
#pragma unroll
  for (int h = 0; h < 2; ++h) {
    const int ntb = h * 4;
    // vv gather for this half (issues before the MFMAs, hides under them)
    float vvf[4][4];
#pragma unroll
    for (int i = 0; i < 4; ++i)
#pragma unroll
      for (int r = 0; r < 4; ++r)
        vvf[i][r] =
            vv[((size_t)(base_n + idxr[r])) * 128 + (ntb + i) * 16 + c];

    floatx4 acch[4];
#pragma unroll
    for (int i = 0; i < 4; ++i) acch[i] = (floatx4){0.f, 0.f, 0.f, 0.f};
    {
      const short* Wst = wsw + 32768;
#pragma unroll
      for (int ks = 0; ks < 4; ++ks) {
        short8 bfr[4];
#pragma unroll
        for (int i = 0; i < 4; ++i)
          bfr[i] = *reinterpret_cast<const short8*>(
              Wst + ((size_t)((ntb + i) * 4 + ks) * 64 + lane) * 8);
#pragma unroll
        for (int i = 0; i < 4; ++i)
          acch[i] = __builtin_amdgcn_mfma_f32_16x16x32_bf16(af[ks], bfr[i],
                                                            acch[i], 0, 0, 0);
      }
    }

#pragma unroll
    for (int i = 0; i < 4; ++i) {
      const int nt = ntb + i;
      const float bg2v = bg2[nt * 16 + c];
      float l0 = (acch[i][0] + bg2v) * inv;
      float l1 = (acch[i][1] + bg2v) * inv;
      float l2 = (acch[i][2] + bg2v) * inv;
      float l3 = (acch[i][3] + bg2v) * inv;
      float m4 = fmaxf(fmaxf(l0, l1), fmaxf(l2, l3));
      m4 = fmaxf(m4, __shfl_xor(m4, 16));
      m4 = fmaxf(m4, __shfl_xor(m4, 32));
      float e0 = expf(l0 - m4), e1 = expf(l1 - m4);
      float e2 = expf(l2 - m4), e3 = expf(l3 - m4);
      float s4 = e0 + e1 + e2 + e3;
      s4 += __shfl_xor(s4, 16);
      s4 += __shfl_xor(s4, 32);
      float rs = 1.f / s4;
      float a0 = e0 * rs, a1 = e1 * rs, a2 = e2 * rs, a3 = e3 * rs;
      size_t base = ((size_t)bn * 16 + g * 4) * 128 + nt * 16 + c;
      out_attn[base + 0 * 128] = a0;
      out_attn[base + 1 * 128] = a1;
      out_attn[base + 2 * 128] = a2;
      out_attn[base + 3 * 128] = a3;
      float r = 0.f;
      r = fmaf(a0, vvf[i][0] + PE[nt][0], r);
      r = fmaf(a1, vvf[i][1] + PE[nt][1], r);
      r = fmaf(a2, vvf[i][2] + PE[nt][2], r);
      r = fmaf(a3, vvf[i][3] + PE[nt][3], r);
      r += __shfl_xor(r, 16);
      r += __shfl_xor(r, 32);
      resv[nt] = r;
    }
  }
#undef STAGE_GEMM

  if (g == 0) {
#pragma unroll
    for (int nt = 0; nt < 8; ++nt)
      res_ws[(size_t)bn * 128 + nt * 16 + c] = resv[nt];
  }
}

// ---------------------------------------------------------------------------
// Epilogue on matrix cores: out_res = res @ W2 + b2 + pre. (unchanged)
// ---------------------------------------------------------------------------
__global__ __launch_bounds__(256, 4) void epilogue_mfma_kernel(
    const float* __restrict__ res_ws, const short* __restrict__ wsplit,
    const float* __restrict__ b2, const float* __restrict__ pre,
    float* __restrict__ out_res) {
  const int wv = threadIdx.x >> 6;
  const int lane = threadIdx.x & 63;
  const int g = lane >> 4;
  const int c = lane & 15;
  const int g0 = blockIdx.x * 16;
  const int nt0 = wv * 2;

  __shared__ __attribute__((aligned(16))) float trans[16 * 132];

  // coalesced load of the 16x128 res block into LDS (float4, 2 per thread)
#pragma unroll
  for (int i = 0; i < 2; ++i) {
    int idx4 = threadIdx.x + i * 256;  // 0..511 float4s
    int row = idx4 >> 5;
    int col4 = idx4 & 31;
    float4 v = *reinterpret_cast<const float4*>(
        res_ws + (size_t)(g0 + row) * 128 + col4 * 4);
    *reinterpret_cast<float4*>(&trans[row * 132 + col4 * 4]) = v;
  }
  __syncthreads();

  short8 ah[4], al[4];
  split_from_lds(trans, c, g, ah, al);

  // prefetch pre + b2 (overlaps the MFMAs)
  float prv0[4], prv1[4];
  const float bb0 = b2[nt0 * 16 + c];
  const float bb1 = b2[(nt0 + 1) * 16 + c];
#pragma unroll
  for (int r = 0; r < 4; ++r) {
    prv0[r] = pre[(size_t)(g0 + g * 4 + r) * 128 + nt0 * 16 + c];
    prv1[r] = pre[(size_t)(g0 + g * 4 + r) * 128 + (nt0 + 1) * 16 + c];
  }

  floatx4 acc0 = (floatx4){0.f, 0.f, 0.f, 0.f};
  floatx4 acc1 = (floatx4){0.f, 0.f, 0.f, 0.f};
  split_gemm2(wsplit + 5 * 32768, nt0, lane, ah, al, acc0, acc1);

#pragma unroll
  for (int r = 0; r < 4; ++r) {
    const int row = g0 + g * 4 + r;
    out_res[(size_t)row * 128 + nt0 * 16 + c] = acc0[r] + bb0 + prv0[r];
    out_res[(size_t)row * 128 + (nt0 + 1) * 16 + c] = acc1[r] + bb1 + prv1[r];
  }
}

extern "C" void kernel_launch(void* const* d_in, const int* in_sizes, int n_in,
                              void* d_out, int out_size, void* d_ws,
                              size_t ws_size, hipStream_t stream) {
  const float* xyz = (const float*)d_in[0];
  const float* W0a = (const float*)d_in[1];
  const float* b0a = (const float*)d_in[2];
  const float* W0b = (const float*)d_in[3];
  const float* b0b = (const float*)d_in[4];
  const float* W1 = (const float*)d_in[5];
  const float* b1 = (const float*)d_in[6];
  const float* W2 = (const float*)d_in[7];
  const float* b2 = (const float*)d_in[8];
  const float* Wd1 = (const float*)d_in[9];
  const float* bd1 = (const float*)d_in[10];
  const float* Wd2 = (const float*)d_in[11];
  const float* bd2 = (const float*)d_in[12];
  const float* Wg1 = (const float*)d_in[13];
  const float* bg1 = (const float*)d_in[14];
  const float* Wg2 = (const float*)d_in[15];
  const float* bg2 = (const float*)d_in[16];
  const float* Wq = (const float*)d_in[17];
  const float* Wk = (const float*)d_in[18];
  const float* Wv = (const float*)d_in[19];

  char* ws = (char*)d_ws;
  int* knn = (int*)ws;                                  // 1 MB
  float* pre = (float*)(ws + (1 << 20));                // 8 MB
  float* qv = (float*)(ws + (9 << 20));                 // 8 MB
  float* kv = (float*)(ws + (17 << 20));                // 8 MB
  float* vv = (float*)(ws + (25 << 20));                // 8 MB
  float* res_ws = (float*)(ws + (33 << 20));            // 8 MB
  short* wsw = (short*)(ws + (41 << 20));               // 96 KB bf16 B-frags
  short* wsplit = (short*)(ws + (41 << 20) + (128 << 10));  // 384 KB split frags

  float* out_res = (float*)d_out;
  float* out_attn = out_res + (size_t)BN * DD;

  hipLaunchKernelGGL(swz_all_kernel, dim3(72), dim3(256), 0, stream, Wd2, Wg1,
                     Wg2, W0b, W1, Wq, Wk, Wv, W2, wsw, wsplit);
  hipLaunchKernelGGL(knn_kernel, dim3(4096), dim3(256), 0, stream, xyz, knn);
  hipLaunchKernelGGL(point_mlp_mfma_kernel, dim3(1024), dim3(256), 0, stream,
                     xyz, W0a, b0a, b0b, b1, wsplit, pre, qv, kv, vv);
  hipLaunchKernelGGL(attn_mfma_kernel, dim3(4096), dim3(256), 0, stream, xyz,
                     knn, qv, kv, vv, wsw, Wd1, bd1, bd2, bg1, bg2, res_ws,
                     out_attn);
  hipLaunchKernelGGL(epilogue_mfma_kernel, dim3(1024), dim3(256), 0, stream,
                     res_ws, wsplit, b2, pre, out_res);
}

// Round 5
// 352.554 us; speedup vs baseline: 1.4315x; 1.0589x over previous
//
#include <hip/hip_runtime.h>
#include <math.h>

#define BB 4
#define NN 4096
#define KNNK 16
#define DD 128
#define BN (BB*NN)

typedef __attribute__((ext_vector_type(8))) short short8;   // 8 bf16
typedef __attribute__((ext_vector_type(4))) float floatx4;  // MFMA acc

__device__ __forceinline__ short f2bf(float x) {
  unsigned u = __float_as_uint(x);
  unsigned r = (u + 0x7fffu + ((u >> 16) & 1u)) >> 16;
  return (short)r;
}

__device__ __forceinline__ float bf2f(short h) {
  return __uint_as_float((unsigned)(unsigned short)h << 16);
}

// Per-wave LDS fence (conv[] is wave-private; verified round 3).
#define LDSFENCE() asm volatile("s_waitcnt lgkmcnt(0)" ::: "memory")

// ---------------------------------------------------------------------------
// Shared split-bf16 GEMM helpers (verified structure).
// ---------------------------------------------------------------------------
__device__ __forceinline__ void split_from_lds(const float* __restrict__ trans,
                                               int c, int g, short8 ah[4],
                                               short8 al[4]) {
#pragma unroll
  for (int s = 0; s < 4; ++s) {
    const float* p_ = &trans[c * 132 + s * 32 + g * 8];
    float4 u0 = *reinterpret_cast<const float4*>(p_);
    float4 u1 = *reinterpret_cast<const float4*>(p_ + 4);
    float tmp[8] = {u0.x, u0.y, u0.z, u0.w, u1.x, u1.y, u1.z, u1.w};
#pragma unroll
    for (int j = 0; j < 8; ++j) {
      short h_ = f2bf(tmp[j]);
      ah[s][j] = h_;
      al[s][j] = f2bf(tmp[j] - bf2f(h_));
    }
  }
}

__device__ __forceinline__ void split_gemm2(const short* __restrict__ Bh,
                                            int nt0, int lane,
                                            const short8 ah[4],
                                            const short8 al[4], floatx4& acc0,
                                            floatx4& acc1) {
  const short* Bl = Bh + 16384;
#pragma unroll
  for (int ks = 0; ks < 4; ++ks) {
    const size_t o0 = ((size_t)((nt0 + 0) * 4 + ks) * 64 + lane) * 8;
    const size_t o1 = ((size_t)((nt0 + 1) * 4 + ks) * 64 + lane) * 8;
    short8 bh0 = *reinterpret_cast<const short8*>(Bh + o0);
    short8 bl0 = *reinterpret_cast<const short8*>(Bl + o0);
    short8 bh1 = *reinterpret_cast<const short8*>(Bh + o1);
    short8 bl1 = *reinterpret_cast<const short8*>(Bl + o1);
    acc0 = __builtin_amdgcn_mfma_f32_16x16x32_bf16(ah[ks], bh0, acc0, 0, 0, 0);
    acc1 = __builtin_amdgcn_mfma_f32_16x16x32_bf16(ah[ks], bh1, acc1, 0, 0, 0);
    acc0 = __builtin_amdgcn_mfma_f32_16x16x32_bf16(ah[ks], bl0, acc0, 0, 0, 0);
    acc1 = __builtin_amdgcn_mfma_f32_16x16x32_bf16(ah[ks], bl1, acc1, 0, 0, 0);
    acc0 = __builtin_amdgcn_mfma_f32_16x16x32_bf16(al[ks], bh0, acc0, 0, 0, 0);
    acc1 = __builtin_amdgcn_mfma_f32_16x16x32_bf16(al[ks], bh1, acc1, 0, 0, 0);
  }
}

// ---------------------------------------------------------------------------
// KNN v4: one WAVE per query, register-only (verified, round-3 exact).
// ---------------------------------------------------------------------------
__device__ __forceinline__ void ced(double& a, double& b) {
  double mn = fmin(a, b);
  double mx = fmax(a, b);
  a = mn;
  b = mx;
}

__device__ __forceinline__ void dsort16(double v[16]) {
#define CE(i, j) ced(v[i], v[j]);
  CE(0, 1) CE(2, 3) CE(4, 5) CE(6, 7) CE(8, 9) CE(10, 11) CE(12, 13) CE(14, 15)
  CE(0, 2) CE(1, 3) CE(4, 6) CE(5, 7) CE(8, 10) CE(9, 11) CE(12, 14) CE(13, 15)
  CE(1, 2) CE(5, 6) CE(9, 10) CE(13, 14)
  CE(0, 4) CE(1, 5) CE(2, 6) CE(3, 7) CE(8, 12) CE(9, 13) CE(10, 14) CE(11, 15)
  CE(2, 4) CE(3, 5) CE(10, 12) CE(11, 13)
  CE(1, 2) CE(3, 4) CE(5, 6) CE(9, 10) CE(11, 12) CE(13, 14)
  CE(0, 8) CE(1, 9) CE(2, 10) CE(3, 11) CE(4, 12) CE(5, 13) CE(6, 14) CE(7, 15)
  CE(4, 8) CE(5, 9) CE(6, 10) CE(7, 11)
  CE(2, 4) CE(3, 5) CE(6, 8) CE(7, 9) CE(10, 12) CE(11, 13)
  CE(1, 2) CE(3, 4) CE(5, 6) CE(7, 8) CE(9, 10) CE(11, 12) CE(13, 14)
#undef CE
}

// sort a 16-element bitonic sequence ascending
__device__ __forceinline__ void dbitonic16(double m[16]) {
#pragma unroll
  for (int s = 8; s >= 1; s >>= 1) {
#pragma unroll
    for (int i = 0; i < 16; ++i) {
      if ((i & s) == 0) ced(m[i], m[i + s]);
    }
  }
}

__global__ __launch_bounds__(256, 4) void knn_kernel(const float* __restrict__ xyz,
                                                     int* __restrict__ knn) {
  const int wv = threadIdx.x >> 6;
  const int lane = threadIdx.x & 63;
  const int q = blockIdx.x * 4 + wv;
  const int b = q >> 12;
  const int n = q & 4095;
  const float* xb = xyz + (size_t)b * NN * 3;

  const float qx = xb[n * 3 + 0], qy = xb[n * 3 + 1], qz = xb[n * 3 + 2];
  const float qsq = __fadd_rn(__fadd_rn(__fmul_rn(qx, qx), __fmul_rn(qy, qy)),
                              __fmul_rn(qz, qz));

  double top[16];
#pragma unroll
  for (int batch = 0; batch < 4; ++batch) {
    double v[16];
#pragma unroll
    for (int i = 0; i < 16; ++i) {
      const int c = (batch * 16 + i) * 64 + lane;
      float cx = xb[c * 3 + 0], cy = xb[c * 3 + 1], cz = xb[c * 3 + 2];
      float csq = __fadd_rn(__fadd_rn(__fmul_rn(cx, cx), __fmul_rn(cy, cy)),
                            __fmul_rn(cz, cz));
      float dot = __fadd_rn(__fadd_rn(__fmul_rn(qx, cx), __fmul_rn(qy, cy)),
                            __fmul_rn(qz, cz));
      float d = __fadd_rn(__fsub_rn(qsq, __fmul_rn(2.0f, dot)), csq);
      unsigned u = __float_as_uint(d);
      u = (u & 0x80000000u) ? ~u : (u | 0x80000000u);  // monotone float->uint
      unsigned long long key =
          0x3FF0000000000000ULL | (((unsigned long long)u << 12) | (unsigned)c);
      v[i] = __longlong_as_double((long long)key);
    }
    dsort16(v);
    if (batch == 0) {
#pragma unroll
      for (int i = 0; i < 16; ++i) top[i] = v[i];
    } else {
      double m[16];
#pragma unroll
      for (int i = 0; i < 16; ++i)
        m[i] = fmin(top[i], v[15 - i]);  // min(asc, desc) -> bitonic lower half
      dbitonic16(m);
#pragma unroll
      for (int i = 0; i < 16; ++i) top[i] = m[i];
    }
  }

#pragma unroll
  for (int mask = 1; mask <= 32; mask <<= 1) {
    double oth[16];
#pragma unroll
    for (int i = 0; i < 16; ++i) {
      double y = __shfl_xor(top[15 - i], mask);
      oth[i] = fmin(y, top[i]);
    }
    dbitonic16(oth);
#pragma unroll
    for (int i = 0; i < 16; ++i) top[i] = oth[i];
  }

  if (lane == 0) {
    int* outp = knn + (size_t)q * KNNK;
#pragma unroll
    for (int k = 0; k < 16; ++k)
      outp[k] = (int)(__double_as_longlong(top[k]) & 0xFFFLL);
  }
}

// ---------------------------------------------------------------------------
// Combined weight pre-swizzle (verified, round-3 exact).
// ---------------------------------------------------------------------------
__global__ void swz_all_kernel(const float* __restrict__ Wd2,
                               const float* __restrict__ Wg1,
                               const float* __restrict__ Wg2,
                               const float* __restrict__ W0b,
                               const float* __restrict__ W1,
                               const float* __restrict__ Wq,
                               const float* __restrict__ Wk,
                               const float* __restrict__ Wv,
                               const float* __restrict__ W2,
                               short* __restrict__ wsw,
                               short* __restrict__ wsplit) {
  int t = blockIdx.x * 256 + threadIdx.x;
  if (t < 3 * 2048) {
    int stage = t / 2048;
    int rem = t % 2048;
    int nt = rem / 256;
    int ks = (rem % 256) / 64;
    int lane = rem % 64;
    const float* W = (stage == 0) ? Wd2 : (stage == 1) ? Wg1 : Wg2;
    short8 o;
#pragma unroll
    for (int j = 0; j < 8; ++j) {
      int k = ks * 32 + (lane >> 4) * 8 + j;
      int n = nt * 16 + (lane & 15);
      o[j] = f2bf(W[k * 128 + n]);
    }
    *reinterpret_cast<short8*>(wsw + (size_t)t * 8) = o;
  } else {
    int u = t - 3 * 2048;
    if (u >= 6 * 2048) return;
    int mat = u / 2048;
    int rem = u % 2048;
    int nt = rem / 256;
    int ks = (rem % 256) / 64;
    int lane = rem % 64;
    const float* W = (mat == 0) ? W0b : (mat == 1) ? W1 : (mat == 2) ? Wq
                     : (mat == 3) ? Wk : (mat == 4) ? Wv : W2;
    short8 hi, lo;
#pragma unroll
    for (int j = 0; j < 8; ++j) {
      int k = ks * 32 + (lane >> 4) * 8 + j;
      int n = nt * 16 + (lane & 15);
      float w = W[k * 128 + n];
      short h = f2bf(w);
      hi[j] = h;
      lo[j] = f2bf(w - bf2f(h));
    }
    *reinterpret_cast<short8*>(wsplit + ((size_t)(2 * mat) * 2048 + rem) * 8) = hi;
    *reinterpret_cast<short8*>(wsplit + ((size_t)(2 * mat + 1) * 2048 + rem) * 8) = lo;
  }
}

// ---------------------------------------------------------------------------
// Point-MLP on matrix cores (verified, round-3 exact standalone kernel).
// ---------------------------------------------------------------------------
__global__ __launch_bounds__(256, 4) void point_mlp_mfma_kernel(
    const float* __restrict__ xyz, const float* __restrict__ W0a,
    const float* __restrict__ b0a, const float* __restrict__ b0b,
    const float* __restrict__ b1, const short* __restrict__ wsplit,
    float* __restrict__ pre, float* __restrict__ qv, float* __restrict__ kv,
    float* __restrict__ vv) {
  const int wv = threadIdx.x >> 6;
  const int lane = threadIdx.x & 63;
  const int g = lane >> 4;   // A-frag k-group / D row-group
  const int c = lane & 15;   // A-frag row / D column-in-tile
  const int g0 = blockIdx.x * 16;
  const int nt0 = wv * 2;

  __shared__ __attribute__((aligned(16))) float trans[16 * 132];
  __shared__ float xs[64];
  if (threadIdx.x < 48) {
    int p = threadIdx.x / 3, cc = threadIdx.x % 3;
    xs[p * 4 + cc] = xyz[(size_t)(g0 + p) * 3 + cc];
  }
  __syncthreads();

  short8 ah[4], al[4];
  // ---- fc0a: relu(xyz @ W0a + b0a), computed directly as split A-frags ----
  {
    const float x0 = xs[c * 4 + 0], x1 = xs[c * 4 + 1], x2 = xs[c * 4 + 2];
#pragma unroll
    for (int s = 0; s < 4; ++s) {
#pragma unroll
      for (int j = 0; j < 8; ++j) {
        const int k = s * 32 + g * 8 + j;
        float v = fmaf(x2, W0a[256 + k],
                       fmaf(x1, W0a[128 + k], fmaf(x0, W0a[k], b0a[k])));
        v = fmaxf(v, 0.f);
        const short h = f2bf(v);
        ah[s][j] = h;
        al[s][j] = f2bf(v - bf2f(h));
      }
    }
  }

  floatx4 acc0, acc1;
  const floatx4 zf = (floatx4){0.f, 0.f, 0.f, 0.f};

  // ---- fc0b: pre = A @ W0b + b0b (no relu; pre stored fp32) ----
  acc0 = zf; acc1 = zf;
  split_gemm2(wsplit + 0 * 32768, nt0, lane, ah, al, acc0, acc1);
  {
    const float bb0 = b0b[nt0 * 16 + c];
    const float bb1 = b0b[(nt0 + 1) * 16 + c];
#pragma unroll
    for (int r = 0; r < 4; ++r) {
      const int row = g * 4 + r;
      float v0 = acc0[r] + bb0;
      float v1 = acc1[r] + bb1;
      pre[(size_t)(g0 + row) * 128 + nt0 * 16 + c] = v0;
      pre[(size_t)(g0 + row) * 128 + (nt0 + 1) * 16 + c] = v1;
      trans[row * 132 + nt0 * 16 + c] = v0;
      trans[row * 132 + (nt0 + 1) * 16 + c] = v1;
    }
  }
  __syncthreads();
  split_from_lds(trans, c, g, ah, al);
  __syncthreads();

  // ---- fc1: x = pre @ W1 + b1 ----
  acc0 = zf; acc1 = zf;
  split_gemm2(wsplit + 1 * 32768, nt0, lane, ah, al, acc0, acc1);
  {
    const float bb0 = b1[nt0 * 16 + c];
    const float bb1 = b1[(nt0 + 1) * 16 + c];
#pragma unroll
    for (int r = 0; r < 4; ++r) {
      const int row = g * 4 + r;
      trans[row * 132 + nt0 * 16 + c] = acc0[r] + bb0;
      trans[row * 132 + (nt0 + 1) * 16 + c] = acc1[r] + bb1;
    }
  }
  __syncthreads();
  split_from_lds(trans, c, g, ah, al);
  __syncthreads();

#define GSTORE(dst)                                                            \
  _Pragma("unroll") for (int r = 0; r < 4; ++r) {                              \
    const int row = g0 + g * 4 + r;                                            \
    dst[(size_t)row * 128 + nt0 * 16 + c] = acc0[r];                           \
    dst[(size_t)row * 128 + (nt0 + 1) * 16 + c] = acc1[r];                     \
  }

  // ---- q / k / v projections (no bias) ----
  acc0 = zf; acc1 = zf;
  split_gemm2(wsplit + 2 * 32768, nt0, lane, ah, al, acc0, acc1);
  GSTORE(qv);

  acc0 = zf; acc1 = zf;
  split_gemm2(wsplit + 3 * 32768, nt0, lane, ah, al, acc0, acc1);
  GSTORE(kv);

  acc0 = zf; acc1 = zf;
  split_gemm2(wsplit + 4 * 32768, nt0, lane, ah, al, acc0, acc1);
  GSTORE(vv);

#undef GSTORE
}

// ---------------------------------------------------------------------------
// Simple per-stage weight staging: each wave copies its quarter of one
// stage's B-fragments (global -> reg -> LDS, immediate write). Double-barrier
// discipline around it; no register lifetime across barriers.
// ---------------------------------------------------------------------------
__device__ __forceinline__ void wstage(const short* __restrict__ wsw_stage,
                                       short* __restrict__ wlds, int wv,
                                       int lane) {
#pragma unroll
  for (int i = 0; i < 8; ++i) {
    short8 w_ = *reinterpret_cast<const short8*>(wsw_stage + wv * 4096 +
                                                 i * 512 + lane * 8);
    *reinterpret_cast<short8*>(&wlds[wv * 4096 + i * 512 + lane * 8]) = w_;
  }
}

// ---------------------------------------------------------------------------
// MFMA attention. Round-5: round-3 verified structure + textbook LDS weight
// staging (the ONLY change vs round 3):
//   wstage(s); barrier; stage-s GEMM reads wlds; conv round-trip (per-wave
//   LDSFENCE, verified); barrier; wstage(s+1); ...
// Collapses ~96 exposed L2 weight loads/wave to 3 rounds of 8 batched loads,
// and cuts weight L2 traffic 4x (per-block instead of per-wave).
// ---------------------------------------------------------------------------
__global__ __launch_bounds__(256, 3) void attn_mfma_kernel(
    const float* __restrict__ xyz, const int* __restrict__ knn,
    const float* __restrict__ qv, const float* __restrict__ kv,
    const float* __restrict__ vv, const short* __restrict__ wsw,
    const float* __restrict__ Wd1, const float* __restrict__ bd1,
    const float* __restrict__ bd2, const float* __restrict__ bg1,
    const float* __restrict__ bg2, float* __restrict__ res_ws,
    float* __restrict__ out_attn) {
  const int wv = threadIdx.x >> 6;
  const int lane = threadIdx.x & 63;
  const int g = lane >> 4;   // lane group 0..3
  const int c = lane & 15;   // column-in-tile / A-row
  const int bn = blockIdx.x * 4 + wv;
  const int b = bn >> 12;
  const int base_n = b << 12;

  __shared__ __attribute__((aligned(16))) short wlds[16384];  // 32KB: 1 stage
  __shared__ __attribute__((aligned(16))) short conv[4][16 * 136];

  // ---- neighbor indices (one 64B line per wave; L2-resident) ----
  const int* knnp = knn + (size_t)bn * 16;
  const int idxn = knnp[c];
  int idxr[4];
#pragma unroll
  for (int r = 0; r < 4; ++r) idxr[r] = knnp[g * 4 + r];

  // ---- kv prefetch into registers ----
  float kvf[8][4];
#pragma unroll
  for (int nt = 0; nt < 8; ++nt)
#pragma unroll
    for (int r = 0; r < 4; ++r)
      kvf[nt][r] = kv[((size_t)(base_n + idxr[r])) * 128 + nt * 16 + c];

  // ---- delta for this lane's neighbor ----
  const float ddx = xyz[(size_t)bn * 3 + 0] - xyz[((size_t)(base_n + idxn)) * 3 + 0];
  const float ddy = xyz[(size_t)bn * 3 + 1] - xyz[((size_t)(base_n + idxn)) * 3 + 1];
  const float ddz = xyz[(size_t)bn * 3 + 2] - xyz[((size_t)(base_n + idxn)) * 3 + 2];

  // ---- P1 = relu(delta @ Wd1 + bd1) directly as A-fragments ----
  short8 af[4];
#pragma unroll
  for (int s = 0; s < 4; ++s) {
#pragma unroll
    for (int j = 0; j < 8; ++j) {
      int d = s * 32 + g * 8 + j;
      float v = fmaf(ddz, Wd1[256 + d],
                     fmaf(ddy, Wd1[128 + d], fmaf(ddx, Wd1[d], bd1[d])));
      af[s][j] = f2bf(fmaxf(v, 0.f));
    }
  }

  // per-nt scalars needed in the H phase
  float qc[8], bd2v[8];
#pragma unroll
  for (int nt = 0; nt < 8; ++nt) {
    qc[nt] = qv[(size_t)bn * 128 + nt * 16 + c];
    bd2v[nt] = bd2[nt * 16 + c];
  }

  floatx4 acc[8];

// grouped ds_read + MFMA over all 8 nt tiles, B from wlds
#define STAGE_GEMM_LDS()                                                       \
  {                                                                            \
    _Pragma("unroll") for (int ks = 0; ks < 4; ++ks) {                         \
      _Pragma("unroll") for (int h2 = 0; h2 < 2; ++h2) {                       \
        short8 bfr[4];                                                         \
        _Pragma("unroll") for (int i = 0; i < 4; ++i)                          \
          bfr[i] = *reinterpret_cast<const short8*>(                           \
              &wlds[((h2 * 4 + i) * 4 + ks) * 512 + lane * 8]);                \
        _Pragma("unroll") for (int i = 0; i < 4; ++i)                          \
          acc[h2 * 4 + i] = __builtin_amdgcn_mfma_f32_16x16x32_bf16(           \
              af[ks], bfr[i], acc[h2 * 4 + i], 0, 0, 0);                       \
      }                                                                        \
    }                                                                          \
  }

  // ---- stage 1: PE = P1 @ Wd2 + bd2 ----
  wstage(wsw, wlds, wv, lane);
  __syncthreads();  // Wd2 ready
#pragma unroll
  for (int nt = 0; nt < 8; ++nt) acc[nt] = (floatx4){0.f, 0.f, 0.f, 0.f};
  STAGE_GEMM_LDS();

  // ---- H = q - kf + PE ; PE kept fp32 ; H -> LDS (bf16, C-layout) ----
  float PE[8][4];
#pragma unroll
  for (int nt = 0; nt < 8; ++nt) {
#pragma unroll
    for (int r = 0; r < 4; ++r) {
      float pe = acc[nt][r] + bd2v[nt];
      PE[nt][r] = pe;
      conv[wv][(g * 4 + r) * 136 + nt * 16 + c] =
          f2bf(qc[nt] - kvf[nt][r] + pe);
    }
  }
  LDSFENCE();
#pragma unroll
  for (int s = 0; s < 4; ++s)
    af[s] = *reinterpret_cast<const short8*>(&conv[wv][c * 136 + s * 32 + g * 8]);

  // ---- stage 2: G = relu(H @ Wg1 + bg1) ----
  __syncthreads();  // all waves done reading Wd2 from wlds
  wstage(wsw + 16384, wlds, wv, lane);
  __syncthreads();  // Wg1 ready
#pragma unroll
  for (int nt = 0; nt < 8; ++nt) acc[nt] = (floatx4){0.f, 0.f, 0.f, 0.f};
  STAGE_GEMM_LDS();
#pragma unroll
  for (int nt = 0; nt < 8; ++nt) {
    const float bg1v = bg1[nt * 16 + c];
#pragma unroll
    for (int r = 0; r < 4; ++r) {
      conv[wv][(g * 4 + r) * 136 + nt * 16 + c] =
          f2bf(fmaxf(acc[nt][r] + bg1v, 0.f));
    }
  }
  LDSFENCE();
#pragma unroll
  for (int s = 0; s < 4; ++s)
    af[s] = *reinterpret_cast<const short8*>(&conv[wv][c * 136 + s * 32 + g * 8]);

  // ---- stage 3: logits = G @ Wg2 + bg2, two 4-nt halves + softmax ----
  __syncthreads();  // all waves done reading Wg1
  wstage(wsw + 32768, wlds, wv, lane);
  __syncthreads();  // Wg2 ready

  const float inv = 0.0883883476483184f;  // 1/sqrt(128)
  float resv[8];
#pragma unroll
  for (int h = 0; h < 2; ++h) {
    const int ntb = h * 4;
    float vvf[4][4];
#pragma unroll
    for (int i = 0; i < 4; ++i)
#pragma unroll
      for (int r = 0; r < 4; ++r)
        vvf[i][r] =
            vv[((size_t)(base_n + idxr[r])) * 128 + (ntb + i) * 16 + c];

    floatx4 acch[4];
#pragma unroll
    for (int i = 0; i < 4; ++i) acch[i] = (floatx4){0.f, 0.f, 0.f, 0.f};
#pragma unroll
    for (int ks = 0; ks < 4; ++ks) {
      short8 bfr[4];
#pragma unroll
      for (int i = 0; i < 4; ++i)
        bfr[i] = *reinterpret_cast<const short8*>(
            &wlds[((ntb + i) * 4 + ks) * 512 + lane * 8]);
#pragma unroll
      for (int i = 0; i < 4; ++i)
        acch[i] = __builtin_amdgcn_mfma_f32_16x16x32_bf16(af[ks], bfr[i],
                                                          acch[i], 0, 0, 0);
    }

#pragma unroll
    for (int i = 0; i < 4; ++i) {
      const int nt = ntb + i;
      const float bg2v = bg2[nt * 16 + c];
      float l0 = (acch[i][0] + bg2v) * inv;
      float l1 = (acch[i][1] + bg2v) * inv;
      float l2 = (acch[i][2] + bg2v) * inv;
      float l3 = (acch[i][3] + bg2v) * inv;
      float m4 = fmaxf(fmaxf(l0, l1), fmaxf(l2, l3));
      m4 = fmaxf(m4, __shfl_xor(m4, 16));
      m4 = fmaxf(m4, __shfl_xor(m4, 32));
      float e0 = expf(l0 - m4), e1 = expf(l1 - m4);
      float e2 = expf(l2 - m4), e3 = expf(l3 - m4);
      float s4 = e0 + e1 + e2 + e3;
      s4 += __shfl_xor(s4, 16);
      s4 += __shfl_xor(s4, 32);
      float rs = 1.f / s4;
      float a0 = e0 * rs, a1 = e1 * rs, a2 = e2 * rs, a3 = e3 * rs;
      size_t base = ((size_t)bn * 16 + g * 4) * 128 + nt * 16 + c;
      out_attn[base + 0 * 128] = a0;
      out_attn[base + 1 * 128] = a1;
      out_attn[base + 2 * 128] = a2;
      out_attn[base + 3 * 128] = a3;
      float r = 0.f;
      r = fmaf(a0, vvf[i][0] + PE[nt][0], r);
      r = fmaf(a1, vvf[i][1] + PE[nt][1], r);
      r = fmaf(a2, vvf[i][2] + PE[nt][2], r);
      r = fmaf(a3, vvf[i][3] + PE[nt][3], r);
      r += __shfl_xor(r, 16);
      r += __shfl_xor(r, 32);
      resv[nt] = r;
    }
  }
#undef STAGE_GEMM_LDS

  if (g == 0) {
#pragma unroll
    for (int nt = 0; nt < 8; ++nt)
      res_ws[(size_t)bn * 128 + nt * 16 + c] = resv[nt];
  }
}

// ---------------------------------------------------------------------------
// Epilogue on matrix cores (verified, round-3 exact).
// ---------------------------------------------------------------------------
__global__ __launch_bounds__(256, 4) void epilogue_mfma_kernel(
    const float* __restrict__ res_ws, const short* __restrict__ wsplit,
    const float* __restrict__ b2, const float* __restrict__ pre,
    float* __restrict__ out_res) {
  const int wv = threadIdx.x >> 6;
  const int lane = threadIdx.x & 63;
  const int g = lane >> 4;
  const int c = lane & 15;
  const int g0 = blockIdx.x * 16;
  const int nt0 = wv * 2;

  __shared__ __attribute__((aligned(16))) float trans[16 * 132];

#pragma unroll
  for (int i = 0; i < 2; ++i) {
    int idx4 = threadIdx.x + i * 256;  // 0..511 float4s
    int row = idx4 >> 5;
    int col4 = idx4 & 31;
    float4 v = *reinterpret_cast<const float4*>(
        res_ws + (size_t)(g0 + row) * 128 + col4 * 4);
    *reinterpret_cast<float4*>(&trans[row * 132 + col4 * 4]) = v;
  }
  __syncthreads();

  short8 ah[4], al[4];
  split_from_lds(trans, c, g, ah, al);

  float prv0[4], prv1[4];
  const float bb0 = b2[nt0 * 16 + c];
  const float bb1 = b2[(nt0 + 1) * 16 + c];
#pragma unroll
  for (int r = 0; r < 4; ++r) {
    prv0[r] = pre[(size_t)(g0 + g * 4 + r) * 128 + nt0 * 16 + c];
    prv1[r] = pre[(size_t)(g0 + g * 4 + r) * 128 + (nt0 + 1) * 16 + c];
  }

  floatx4 acc0 = (floatx4){0.f, 0.f, 0.f, 0.f};
  floatx4 acc1 = (floatx4){0.f, 0.f, 0.f, 0.f};
  split_gemm2(wsplit + 5 * 32768, nt0, lane, ah, al, acc0, acc1);

#pragma unroll
  for (int r = 0; r < 4; ++r) {
    const int row = g0 + g * 4 + r;
    out_res[(size_t)row * 128 + nt0 * 16 + c] = acc0[r] + bb0 + prv0[r];
    out_res[(size_t)row * 128 + (nt0 + 1) * 16 + c] = acc1[r] + bb1 + prv1[r];
  }
}

extern "C" void kernel_launch(void* const* d_in, const int* in_sizes, int n_in,
                              void* d_out, int out_size, void* d_ws,
                              size_t ws_size, hipStream_t stream) {
  const float* xyz = (const float*)d_in[0];
  const float* W0a = (const float*)d_in[1];
  const float* b0a = (const float*)d_in[2];
  const float* W0b = (const float*)d_in[3];
  const float* b0b = (const float*)d_in[4];
  const float* W1 = (const float*)d_in[5];
  const float* b1 = (const float*)d_in[6];
  const float* W2 = (const float*)d_in[7];
  const float* b2 = (const float*)d_in[8];
  const float* Wd1 = (const float*)d_in[9];
  const float* bd1 = (const float*)d_in[10];
  const float* Wd2 = (const float*)d_in[11];
  const float* bd2 = (const float*)d_in[12];
  const float* Wg1 = (const float*)d_in[13];
  const float* bg1 = (const float*)d_in[14];
  const float* Wg2 = (const float*)d_in[15];
  const float* bg2 = (const float*)d_in[16];
  const float* Wq = (const float*)d_in[17];
  const float* Wk = (const float*)d_in[18];
  const float* Wv = (const float*)d_in[19];

  char* ws = (char*)d_ws;
  int* knn = (int*)ws;                                  // 1 MB
  float* pre = (float*)(ws + (1 << 20));                // 8 MB
  float* qv = (float*)(ws + (9 << 20));                 // 8 MB
  float* kv = (float*)(ws + (17 << 20));                // 8 MB
  float* vv = (float*)(ws + (25 << 20));                // 8 MB
  float* res_ws = (float*)(ws + (33 << 20));            // 8 MB
  short* wsw = (short*)(ws + (41 << 20));               // 96 KB bf16 B-frags
  short* wsplit = (short*)(ws + (41 << 20) + (128 << 10));  // 384 KB split frags

  float* out_res = (float*)d_out;
  float* out_attn = out_res + (size_t)BN * DD;

  hipLaunchKernelGGL(swz_all_kernel, dim3(72), dim3(256), 0, stream, Wd2, Wg1,
                     Wg2, W0b, W1, Wq, Wk, Wv, W2, wsw, wsplit);
  hipLaunchKernelGGL(knn_kernel, dim3(4096), dim3(256), 0, stream, xyz, knn);
  hipLaunchKernelGGL(point_mlp_mfma_kernel, dim3(1024), dim3(256), 0, stream,
                     xyz, W0a, b0a, b0b, b1, wsplit, pre, qv, kv, vv);
  hipLaunchKernelGGL(attn_mfma_kernel, dim3(4096), dim3(256), 0, stream, xyz,
                     knn, qv, kv, vv, wsw, Wd1, bd1, bd2, bg1, bg2, res_ws,
                     out_attn);
  hipLaunchKernelGGL(epilogue_mfma_kernel, dim3(1024), dim3(256), 0, stream,
                     res_ws, wsplit, b2, pre, out_res);
}

// Round 7
// 345.939 us; speedup vs baseline: 1.4589x; 1.0191x over previous
//
#include <hip/hip_runtime.h>
#include <math.h>

#define BB 4
#define NN 4096
#define KNNK 16
#define DD 128
#define BN (BB*NN)

typedef __attribute__((ext_vector_type(8))) short short8;   // 8 bf16
typedef __attribute__((ext_vector_type(4))) float floatx4;  // MFMA acc

__device__ __forceinline__ short f2bf(float x) {
  unsigned u = __float_as_uint(x);
  unsigned r = (u + 0x7fffu + ((u >> 16) & 1u)) >> 16;
  return (short)r;
}

__device__ __forceinline__ float bf2f(short h) {
  return __uint_as_float((unsigned)(unsigned short)h << 16);
}

// Per-wave LDS fence (conv[] is wave-private; verified round 3/5).
#define LDSFENCE() asm volatile("s_waitcnt lgkmcnt(0)" ::: "memory")

// ---------------------------------------------------------------------------
// Shared split-bf16 GEMM helpers (verified structure).
// ---------------------------------------------------------------------------
__device__ __forceinline__ void split_from_lds(const float* __restrict__ trans,
                                               int c, int g, short8 ah[4],
                                               short8 al[4]) {
#pragma unroll
  for (int s = 0; s < 4; ++s) {
    const float* p_ = &trans[c * 132 + s * 32 + g * 8];
    float4 u0 = *reinterpret_cast<const float4*>(p_);
    float4 u1 = *reinterpret_cast<const float4*>(p_ + 4);
    float tmp[8] = {u0.x, u0.y, u0.z, u0.w, u1.x, u1.y, u1.z, u1.w};
#pragma unroll
    for (int j = 0; j < 8; ++j) {
      short h_ = f2bf(tmp[j]);
      ah[s][j] = h_;
      al[s][j] = f2bf(tmp[j] - bf2f(h_));
    }
  }
}

__device__ __forceinline__ void split_gemm2(const short* __restrict__ Bh,
                                            int nt0, int lane,
                                            const short8 ah[4],
                                            const short8 al[4], floatx4& acc0,
                                            floatx4& acc1) {
  const short* Bl = Bh + 16384;
#pragma unroll
  for (int ks = 0; ks < 4; ++ks) {
    const size_t o0 = ((size_t)((nt0 + 0) * 4 + ks) * 64 + lane) * 8;
    const size_t o1 = ((size_t)((nt0 + 1) * 4 + ks) * 64 + lane) * 8;
    short8 bh0 = *reinterpret_cast<const short8*>(Bh + o0);
    short8 bl0 = *reinterpret_cast<const short8*>(Bl + o0);
    short8 bh1 = *reinterpret_cast<const short8*>(Bh + o1);
    short8 bl1 = *reinterpret_cast<const short8*>(Bl + o1);
    acc0 = __builtin_amdgcn_mfma_f32_16x16x32_bf16(ah[ks], bh0, acc0, 0, 0, 0);
    acc1 = __builtin_amdgcn_mfma_f32_16x16x32_bf16(ah[ks], bh1, acc1, 0, 0, 0);
    acc0 = __builtin_amdgcn_mfma_f32_16x16x32_bf16(ah[ks], bl0, acc0, 0, 0, 0);
    acc1 = __builtin_amdgcn_mfma_f32_16x16x32_bf16(ah[ks], bl1, acc1, 0, 0, 0);
    acc0 = __builtin_amdgcn_mfma_f32_16x16x32_bf16(al[ks], bh0, acc0, 0, 0, 0);
    acc1 = __builtin_amdgcn_mfma_f32_16x16x32_bf16(al[ks], bh1, acc1, 0, 0, 0);
  }
}

// ---------------------------------------------------------------------------
// KNN v5: FOUR queries per wave (16 lanes each). Same f64 order-preserving
// key (monotone32(d)<<12 | idx, all keys normal f64 in [1,2)), same sort
// networks. 256 candidates per lane-group element -> 16 batches of 16;
// cross-lane merge is 4 levels (masks 1,2,4,8) instead of 6. Per-query
// compare-exchange count drops 684 -> 480 (-30%). Batch loop kept rolled
// (first batch peeled) for I$ footprint.
// ---------------------------------------------------------------------------
__device__ __forceinline__ void ced(double& a, double& b) {
  double mn = fmin(a, b);
  double mx = fmax(a, b);
  a = mn;
  b = mx;
}

__device__ __forceinline__ void dsort16(double v[16]) {
#define CE(i, j) ced(v[i], v[j]);
  CE(0, 1) CE(2, 3) CE(4, 5) CE(6, 7) CE(8, 9) CE(10, 11) CE(12, 13) CE(14, 15)
  CE(0, 2) CE(1, 3) CE(4, 6) CE(5, 7) CE(8, 10) CE(9, 11) CE(12, 14) CE(13, 15)
  CE(1, 2) CE(5, 6) CE(9, 10) CE(13, 14)
  CE(0, 4) CE(1, 5) CE(2, 6) CE(3, 7) CE(8, 12) CE(9, 13) CE(10, 14) CE(11, 15)
  CE(2, 4) CE(3, 5) CE(10, 12) CE(11, 13)
  CE(1, 2) CE(3, 4) CE(5, 6) CE(9, 10) CE(11, 12) CE(13, 14)
  CE(0, 8) CE(1, 9) CE(2, 10) CE(3, 11) CE(4, 12) CE(5, 13) CE(6, 14) CE(7, 15)
  CE(4, 8) CE(5, 9) CE(6, 10) CE(7, 11)
  CE(2, 4) CE(3, 5) CE(6, 8) CE(7, 9) CE(10, 12) CE(11, 13)
  CE(1, 2) CE(3, 4) CE(5, 6) CE(7, 8) CE(9, 10) CE(11, 12) CE(13, 14)
#undef CE
}

// sort a 16-element bitonic sequence ascending
__device__ __forceinline__ void dbitonic16(double m[16]) {
#pragma unroll
  for (int s = 8; s >= 1; s >>= 1) {
#pragma unroll
    for (int i = 0; i < 16; ++i) {
      if ((i & s) == 0) ced(m[i], m[i + s]);
    }
  }
}

__global__ __launch_bounds__(256, 4) void knn_kernel(const float* __restrict__ xyz,
                                                     int* __restrict__ knn) {
  const int wv = threadIdx.x >> 6;
  const int lane = threadIdx.x & 63;
  const int ln = lane & 15;   // lane within 16-lane query group
  const int qg = lane >> 4;   // query group 0..3 within wave
  const int q = blockIdx.x * 16 + wv * 4 + qg;
  const int b = q >> 12;
  const int n = q & 4095;
  const float* xb = xyz + (size_t)b * NN * 3;

  const float qx = xb[n * 3 + 0], qy = xb[n * 3 + 1], qz = xb[n * 3 + 2];
  const float qsq = __fadd_rn(__fadd_rn(__fmul_rn(qx, qx), __fmul_rn(qy, qy)),
                              __fmul_rn(qz, qz));

#define LOADBATCH(batch)                                                       \
  _Pragma("unroll") for (int i = 0; i < 16; ++i) {                             \
    const int c = ((batch) * 16 + i) * 16 + ln;                                \
    float cx = xb[c * 3 + 0], cy = xb[c * 3 + 1], cz = xb[c * 3 + 2];          \
    float csq = __fadd_rn(__fadd_rn(__fmul_rn(cx, cx), __fmul_rn(cy, cy)),     \
                          __fmul_rn(cz, cz));                                  \
    float dot = __fadd_rn(__fadd_rn(__fmul_rn(qx, cx), __fmul_rn(qy, cy)),     \
                          __fmul_rn(qz, cz));                                  \
    float d = __fadd_rn(__fsub_rn(qsq, __fmul_rn(2.0f, dot)), csq);            \
    unsigned u = __float_as_uint(d);                                           \
    u = (u & 0x80000000u) ? ~u : (u | 0x80000000u);                            \
    unsigned long long key =                                                   \
        0x3FF0000000000000ULL | (((unsigned long long)u << 12) | (unsigned)c); \
    v[i] = __longlong_as_double((long long)key);                               \
  }

  double top[16];
  {
    double v[16];
    LOADBATCH(0);
    dsort16(v);
#pragma unroll
    for (int i = 0; i < 16; ++i) top[i] = v[i];
  }
#pragma unroll 1
  for (int batch = 1; batch < 16; ++batch) {
    double v[16];
    LOADBATCH(batch);
    dsort16(v);
    double m[16];
#pragma unroll
    for (int i = 0; i < 16; ++i)
      m[i] = fmin(top[i], v[15 - i]);  // min(asc, desc) -> bitonic lower half
    dbitonic16(m);
#pragma unroll
    for (int i = 0; i < 16; ++i) top[i] = m[i];
  }
#undef LOADBATCH

  // cross-lane merge within the 16-lane query group (masks 1,2,4,8)
#pragma unroll
  for (int mask = 1; mask <= 8; mask <<= 1) {
    double oth[16];
#pragma unroll
    for (int i = 0; i < 16; ++i) {
      double y = __shfl_xor(top[15 - i], mask);
      oth[i] = fmin(y, top[i]);
    }
    dbitonic16(oth);
#pragma unroll
    for (int i = 0; i < 16; ++i) top[i] = oth[i];
  }

  if (ln == 0) {
    int* outp = knn + (size_t)q * KNNK;
#pragma unroll
    for (int k = 0; k < 16; ++k)
      outp[k] = (int)(__double_as_longlong(top[k]) & 0xFFFLL);
  }
}

// ---------------------------------------------------------------------------
// Combined weight pre-swizzle (verified, round-5 exact).
// ---------------------------------------------------------------------------
__global__ void swz_all_kernel(const float* __restrict__ Wd2,
                               const float* __restrict__ Wg1,
                               const float* __restrict__ Wg2,
                               const float* __restrict__ W0b,
                               const float* __restrict__ W1,
                               const float* __restrict__ Wq,
                               const float* __restrict__ Wk,
                               const float* __restrict__ Wv,
                               const float* __restrict__ W2,
                               short* __restrict__ wsw,
                               short* __restrict__ wsplit) {
  int t = blockIdx.x * 256 + threadIdx.x;
  if (t < 3 * 2048) {
    int stage = t / 2048;
    int rem = t % 2048;
    int nt = rem / 256;
    int ks = (rem % 256) / 64;
    int lane = rem % 64;
    const float* W = (stage == 0) ? Wd2 : (stage == 1) ? Wg1 : Wg2;
    short8 o;
#pragma unroll
    for (int j = 0; j < 8; ++j) {
      int k = ks * 32 + (lane >> 4) * 8 + j;
      int n = nt * 16 + (lane & 15);
      o[j] = f2bf(W[k * 128 + n]);
    }
    *reinterpret_cast<short8*>(wsw + (size_t)t * 8) = o;
  } else {
    int u = t - 3 * 2048;
    if (u >= 6 * 2048) return;
    int mat = u / 2048;
    int rem = u % 2048;
    int nt = rem / 256;
    int ks = (rem % 256) / 64;
    int lane = rem % 64;
    const float* W = (mat == 0) ? W0b : (mat == 1) ? W1 : (mat == 2) ? Wq
                     : (mat == 3) ? Wk : (mat == 4) ? Wv : W2;
    short8 hi, lo;
#pragma unroll
    for (int j = 0; j < 8; ++j) {
      int k = ks * 32 + (lane >> 4) * 8 + j;
      int n = nt * 16 + (lane & 15);
      float w = W[k * 128 + n];
      short h = f2bf(w);
      hi[j] = h;
      lo[j] = f2bf(w - bf2f(h));
    }
    *reinterpret_cast<short8*>(wsplit + ((size_t)(2 * mat) * 2048 + rem) * 8) = hi;
    *reinterpret_cast<short8*>(wsplit + ((size_t)(2 * mat + 1) * 2048 + rem) * 8) = lo;
  }
}

// ---------------------------------------------------------------------------
// Point-MLP on matrix cores (verified, round-5 exact).
// ---------------------------------------------------------------------------
__global__ __launch_bounds__(256, 4) void point_mlp_mfma_kernel(
    const float* __restrict__ xyz, const float* __restrict__ W0a,
    const float* __restrict__ b0a, const float* __restrict__ b0b,
    const float* __restrict__ b1, const short* __restrict__ wsplit,
    float* __restrict__ pre, float* __restrict__ qv, float* __restrict__ kv,
    float* __restrict__ vv) {
  const int wv = threadIdx.x >> 6;
  const int lane = threadIdx.x & 63;
  const int g = lane >> 4;   // A-frag k-group / D row-group
  const int c = lane & 15;   // A-frag row / D column-in-tile
  const int g0 = blockIdx.x * 16;
  const int nt0 = wv * 2;

  __shared__ __attribute__((aligned(16))) float trans[16 * 132];
  __shared__ float xs[64];
  if (threadIdx.x < 48) {
    int p = threadIdx.x / 3, cc = threadIdx.x % 3;
    xs[p * 4 + cc] = xyz[(size_t)(g0 + p) * 3 + cc];
  }
  __syncthreads();

  short8 ah[4], al[4];
  // ---- fc0a: relu(xyz @ W0a + b0a), computed directly as split A-frags ----
  {
    const float x0 = xs[c * 4 + 0], x1 = xs[c * 4 + 1], x2 = xs[c * 4 + 2];
#pragma unroll
    for (int s = 0; s < 4; ++s) {
#pragma unroll
      for (int j = 0; j < 8; ++j) {
        const int k = s * 32 + g * 8 + j;
        float v = fmaf(x2, W0a[256 + k],
                       fmaf(x1, W0a[128 + k], fmaf(x0, W0a[k], b0a[k])));
        v = fmaxf(v, 0.f);
        const short h = f2bf(v);
        ah[s][j] = h;
        al[s][j] = f2bf(v - bf2f(h));
      }
    }
  }

  floatx4 acc0, acc1;
  const floatx4 zf = (floatx4){0.f, 0.f, 0.f, 0.f};

  // ---- fc0b: pre = A @ W0b + b0b (no relu; pre stored fp32) ----
  acc0 = zf; acc1 = zf;
  split_gemm2(wsplit + 0 * 32768, nt0, lane, ah, al, acc0, acc1);
  {
    const float bb0 = b0b[nt0 * 16 + c];
    const float bb1 = b0b[(nt0 + 1) * 16 + c];
#pragma unroll
    for (int r = 0; r < 4; ++r) {
      const int row = g * 4 + r;
      float v0 = acc0[r] + bb0;
      float v1 = acc1[r] + bb1;
      pre[(size_t)(g0 + row) * 128 + nt0 * 16 + c] = v0;
      pre[(size_t)(g0 + row) * 128 + (nt0 + 1) * 16 + c] = v1;
      trans[row * 132 + nt0 * 16 + c] = v0;
      trans[row * 132 + (nt0 + 1) * 16 + c] = v1;
    }
  }
  __syncthreads();
  split_from_lds(trans, c, g, ah, al);
  __syncthreads();

  // ---- fc1: x = pre @ W1 + b1 ----
  acc0 = zf; acc1 = zf;
  split_gemm2(wsplit + 1 * 32768, nt0, lane, ah, al, acc0, acc1);
  {
    const float bb0 = b1[nt0 * 16 + c];
    const float bb1 = b1[(nt0 + 1) * 16 + c];
#pragma unroll
    for (int r = 0; r < 4; ++r) {
      const int row = g * 4 + r;
      trans[row * 132 + nt0 * 16 + c] = acc0[r] + bb0;
      trans[row * 132 + (nt0 + 1) * 16 + c] = acc1[r] + bb1;
    }
  }
  __syncthreads();
  split_from_lds(trans, c, g, ah, al);
  __syncthreads();

#define GSTORE(dst)                                                            \
  _Pragma("unroll") for (int r = 0; r < 4; ++r) {                              \
    const int row = g0 + g * 4 + r;                                            \
    dst[(size_t)row * 128 + nt0 * 16 + c] = acc0[r];                           \
    dst[(size_t)row * 128 + (nt0 + 1) * 16 + c] = acc1[r];                     \
  }

  // ---- q / k / v projections (no bias) ----
  acc0 = zf; acc1 = zf;
  split_gemm2(wsplit + 2 * 32768, nt0, lane, ah, al, acc0, acc1);
  GSTORE(qv);

  acc0 = zf; acc1 = zf;
  split_gemm2(wsplit + 3 * 32768, nt0, lane, ah, al, acc0, acc1);
  GSTORE(kv);

  acc0 = zf; acc1 = zf;
  split_gemm2(wsplit + 4 * 32768, nt0, lane, ah, al, acc0, acc1);
  GSTORE(vv);

#undef GSTORE
}

// ---------------------------------------------------------------------------
// Simple per-stage weight staging (verified, round-5 exact).
// ---------------------------------------------------------------------------
__device__ __forceinline__ void wstage(const short* __restrict__ wsw_stage,
                                       short* __restrict__ wlds, int wv,
                                       int lane) {
#pragma unroll
  for (int i = 0; i < 8; ++i) {
    short8 w_ = *reinterpret_cast<const short8*>(wsw_stage + wv * 4096 +
                                                 i * 512 + lane * 8);
    *reinterpret_cast<short8*>(&wlds[wv * 4096 + i * 512 + lane * 8]) = w_;
  }
}

// ---------------------------------------------------------------------------
// MFMA attention (verified, round-5 exact).
// ---------------------------------------------------------------------------
__global__ __launch_bounds__(256, 3) void attn_mfma_kernel(
    const float* __restrict__ xyz, const int* __restrict__ knn,
    const float* __restrict__ qv, const float* __restrict__ kv,
    const float* __restrict__ vv, const short* __restrict__ wsw,
    const float* __restrict__ Wd1, const float* __restrict__ bd1,
    const float* __restrict__ bd2, const float* __restrict__ bg1,
    const float* __restrict__ bg2, float* __restrict__ res_ws,
    float* __restrict__ out_attn) {
  const int wv = threadIdx.x >> 6;
  const int lane = threadIdx.x & 63;
  const int g = lane >> 4;   // lane group 0..3
  const int c = lane & 15;   // column-in-tile / A-row
  const int bn = blockIdx.x * 4 + wv;
  const int b = bn >> 12;
  const int base_n = b << 12;

  __shared__ __attribute__((aligned(16))) short wlds[16384];  // 32KB: 1 stage
  __shared__ __attribute__((aligned(16))) short conv[4][16 * 136];

  // ---- neighbor indices (one 64B line per wave; L2-resident) ----
  const int* knnp = knn + (size_t)bn * 16;
  const int idxn = knnp[c];
  int idxr[4];
#pragma unroll
  for (int r = 0; r < 4; ++r) idxr[r] = knnp[g * 4 + r];

  // ---- kv prefetch into registers ----
  float kvf[8][4];
#pragma unroll
  for (int nt = 0; nt < 8; ++nt)
#pragma unroll
    for (int r = 0; r < 4; ++r)
      kvf[nt][r] = kv[((size_t)(base_n + idxr[r])) * 128 + nt * 16 + c];

  // ---- delta for this lane's neighbor ----
  const float ddx = xyz[(size_t)bn * 3 + 0] - xyz[((size_t)(base_n + idxn)) * 3 + 0];
  const float ddy = xyz[(size_t)bn * 3 + 1] - xyz[((size_t)(base_n + idxn)) * 3 + 1];
  const float ddz = xyz[(size_t)bn * 3 + 2] - xyz[((size_t)(base_n + idxn)) * 3 + 2];

  // ---- P1 = relu(delta @ Wd1 + bd1) directly as A-fragments ----
  short8 af[4];
#pragma unroll
  for (int s = 0; s < 4; ++s) {
#pragma unroll
    for (int j = 0; j < 8; ++j) {
      int d = s * 32 + g * 8 + j;
      float v = fmaf(ddz, Wd1[256 + d],
                     fmaf(ddy, Wd1[128 + d], fmaf(ddx, Wd1[d], bd1[d])));
      af[s][j] = f2bf(fmaxf(v, 0.f));
    }
  }

  // per-nt scalars needed in the H phase
  float qc[8], bd2v[8];
#pragma unroll
  for (int nt = 0; nt < 8; ++nt) {
    qc[nt] = qv[(size_t)bn * 128 + nt * 16 + c];
    bd2v[nt] = bd2[nt * 16 + c];
  }

  floatx4 acc[8];

// grouped ds_read + MFMA over all 8 nt tiles, B from wlds
#define STAGE_GEMM_LDS()                                                       \
  {                                                                            \
    _Pragma("unroll") for (int ks = 0; ks < 4; ++ks) {                         \
      _Pragma("unroll") for (int h2 = 0; h2 < 2; ++h2) {                       \
        short8 bfr[4];                                                         \
        _Pragma("unroll") for (int i = 0; i < 4; ++i)                          \
          bfr[i] = *reinterpret_cast<const short8*>(                           \
              &wlds[((h2 * 4 + i) * 4 + ks) * 512 + lane * 8]);                \
        _Pragma("unroll") for (int i = 0; i < 4; ++i)                          \
          acc[h2 * 4 + i] = __builtin_amdgcn_mfma_f32_16x16x32_bf16(           \
              af[ks], bfr[i], acc[h2 * 4 + i], 0, 0, 0);                       \
      }                                                                        \
    }                                                                          \
  }

  // ---- stage 1: PE = P1 @ Wd2 + bd2 ----
  wstage(wsw, wlds, wv, lane);
  __syncthreads();  // Wd2 ready
#pragma unroll
  for (int nt = 0; nt < 8; ++nt) acc[nt] = (floatx4){0.f, 0.f, 0.f, 0.f};
  STAGE_GEMM_LDS();

  // ---- H = q - kf + PE ; PE kept fp32 ; H -> LDS (bf16, C-layout) ----
  float PE[8][4];
#pragma unroll
  for (int nt = 0; nt < 8; ++nt) {
#pragma unroll
    for (int r = 0; r < 4; ++r) {
      float pe = acc[nt][r] + bd2v[nt];
      PE[nt][r] = pe;
      conv[wv][(g * 4 + r) * 136 + nt * 16 + c] =
          f2bf(qc[nt] - kvf[nt][r] + pe);
    }
  }
  LDSFENCE();
#pragma unroll
  for (int s = 0; s < 4; ++s)
    af[s] = *reinterpret_cast<const short8*>(&conv[wv][c * 136 + s * 32 + g * 8]);

  // ---- stage 2: G = relu(H @ Wg1 + bg1) ----
  __syncthreads();  // all waves done reading Wd2 from wlds
  wstage(wsw + 16384, wlds, wv, lane);
  __syncthreads();  // Wg1 ready
#pragma unroll
  for (int nt = 0; nt < 8; ++nt) acc[nt] = (floatx4){0.f, 0.f, 0.f, 0.f};
  STAGE_GEMM_LDS();
#pragma unroll
  for (int nt = 0; nt < 8; ++nt) {
    const float bg1v = bg1[nt * 16 + c];
#pragma unroll
    for (int r = 0; r < 4; ++r) {
      conv[wv][(g * 4 + r) * 136 + nt * 16 + c] =
          f2bf(fmaxf(acc[nt][r] + bg1v, 0.f));
    }
  }
  LDSFENCE();
#pragma unroll
  for (int s = 0; s < 4; ++s)
    af[s] = *reinterpret_cast<const short8*>(&conv[wv][c * 136 + s * 32 + g * 8]);

  // ---- stage 3: logits = G @ Wg2 + bg2, two 4-nt halves + softmax ----
  __syncthreads();  // all waves done reading Wg1
  wstage(wsw + 32768, wlds, wv, lane);
  __syncthreads();  // Wg2 ready

  const float inv = 0.0883883476483184f;  // 1/sqrt(128)
  float resv[8];
#pragma unroll
  for (int h = 0; h < 2; ++h) {
    const int ntb = h * 4;
    float vvf[4][4];
#pragma unroll
    for (int i = 0; i < 4; ++i)
#pragma unroll
      for (int r = 0; r < 4; ++r)
        vvf[i][r] =
            vv[((size_t)(base_n + idxr[r])) * 128 + (ntb + i) * 16 + c];

    floatx4 acch[4];
#pragma unroll
    for (int i = 0; i < 4; ++i) acch[i] = (floatx4){0.f, 0.f, 0.f, 0.f};
#pragma unroll
    for (int ks = 0; ks < 4; ++ks) {
      short8 bfr[4];
#pragma unroll
      for (int i = 0; i < 4; ++i)
        bfr[i] = *reinterpret_cast<const short8*>(
            &wlds[((ntb + i) * 4 + ks) * 512 + lane * 8]);
#pragma unroll
      for (int i = 0; i < 4; ++i)
        acch[i] = __builtin_amdgcn_mfma_f32_16x16x32_bf16(af[ks], bfr[i],
                                                          acch[i], 0, 0, 0);
    }

#pragma unroll
    for (int i = 0; i < 4; ++i) {
      const int nt = ntb + i;
      const float bg2v = bg2[nt * 16 + c];
      float l0 = (acch[i][0] + bg2v) * inv;
      float l1 = (acch[i][1] + bg2v) * inv;
      float l2 = (acch[i][2] + bg2v) * inv;
      float l3 = (acch[i][3] + bg2v) * inv;
      float m4 = fmaxf(fmaxf(l0, l1), fmaxf(l2, l3));
      m4 = fmaxf(m4, __shfl_xor(m4, 16));
      m4 = fmaxf(m4, __shfl_xor(m4, 32));
      float e0 = expf(l0 - m4), e1 = expf(l1 - m4);
      float e2 = expf(l2 - m4), e3 = expf(l3 - m4);
      float s4 = e0 + e1 + e2 + e3;
      s4 += __shfl_xor(s4, 16);
      s4 += __shfl_xor(s4, 32);
      float rs = 1.f / s4;
      float a0 = e0 * rs, a1 = e1 * rs, a2 = e2 * rs, a3 = e3 * rs;
      size_t base = ((size_t)bn * 16 + g * 4) * 128 + nt * 16 + c;
      out_attn[base + 0 * 128] = a0;
      out_attn[base + 1 * 128] = a1;
      out_attn[base + 2 * 128] = a2;
      out_attn[base + 3 * 128] = a3;
      float r = 0.f;
      r = fmaf(a0, vvf[i][0] + PE[nt][0], r);
      r = fmaf(a1, vvf[i][1] + PE[nt][1], r);
      r = fmaf(a2, vvf[i][2] + PE[nt][2], r);
      r = fmaf(a3, vvf[i][3] + PE[nt][3], r);
      r += __shfl_xor(r, 16);
      r += __shfl_xor(r, 32);
      resv[nt] = r;
    }
  }
#undef STAGE_GEMM_LDS

  if (g == 0) {
#pragma unroll
    for (int nt = 0; nt < 8; ++nt)
      res_ws[(size_t)bn * 128 + nt * 16 + c] = resv[nt];
  }
}

// ---------------------------------------------------------------------------
// Epilogue on matrix cores (verified, round-5 exact).
// ---------------------------------------------------------------------------
__global__ __launch_bounds__(256, 4) void epilogue_mfma_kernel(
    const float* __restrict__ res_ws, const short* __restrict__ wsplit,
    const float* __restrict__ b2, const float* __restrict__ pre,
    float* __restrict__ out_res) {
  const int wv = threadIdx.x >> 6;
  const int lane = threadIdx.x & 63;
  const int g = lane >> 4;
  const int c = lane & 15;
  const int g0 = blockIdx.x * 16;
  const int nt0 = wv * 2;

  __shared__ __attribute__((aligned(16))) float trans[16 * 132];

#pragma unroll
  for (int i = 0; i < 2; ++i) {
    int idx4 = threadIdx.x + i * 256;  // 0..511 float4s
    int row = idx4 >> 5;
    int col4 = idx4 & 31;
    float4 v = *reinterpret_cast<const float4*>(
        res_ws + (size_t)(g0 + row) * 128 + col4 * 4);
    *reinterpret_cast<float4*>(&trans[row * 132 + col4 * 4]) = v;
  }
  __syncthreads();

  short8 ah[4], al[4];
  split_from_lds(trans, c, g, ah, al);

  float prv0[4], prv1[4];
  const float bb0 = b2[nt0 * 16 + c];
  const float bb1 = b2[(nt0 + 1) * 16 + c];
#pragma unroll
  for (int r = 0; r < 4; ++r) {
    prv0[r] = pre[(size_t)(g0 + g * 4 + r) * 128 + nt0 * 16 + c];
    prv1[r] = pre[(size_t)(g0 + g * 4 + r) * 128 + (nt0 + 1) * 16 + c];
  }

  floatx4 acc0 = (floatx4){0.f, 0.f, 0.f, 0.f};
  floatx4 acc1 = (floatx4){0.f, 0.f, 0.f, 0.f};
  split_gemm2(wsplit + 5 * 32768, nt0, lane, ah, al, acc0, acc1);

#pragma unroll
  for (int r = 0; r < 4; ++r) {
    const int row = g0 + g * 4 + r;
    out_res[(size_t)row * 128 + nt0 * 16 + c] = acc0[r] + bb0 + prv0[r];
    out_res[(size_t)row * 128 + (nt0 + 1) * 16 + c] = acc1[r] + bb1 + prv1[r];
  }
}

extern "C" void kernel_launch(void* const* d_in, const int* in_sizes, int n_in,
                              void* d_out, int out_size, void* d_ws,
                              size_t ws_size, hipStream_t stream) {
  const float* xyz = (const float*)d_in[0];
  const float* W0a = (const float*)d_in[1];
  const float* b0a = (const float*)d_in[2];
  const float* W0b = (const float*)d_in[3];
  const float* b0b = (const float*)d_in[4];
  const float* W1 = (const float*)d_in[5];
  const float* b1 = (const float*)d_in[6];
  const float* W2 = (const float*)d_in[7];
  const float* b2 = (const float*)d_in[8];
  const float* Wd1 = (const float*)d_in[9];
  const float* bd1 = (const float*)d_in[10];
  const float* Wd2 = (const float*)d_in[11];
  const float* bd2 = (const float*)d_in[12];
  const float* Wg1 = (const float*)d_in[13];
  const float* bg1 = (const float*)d_in[14];
  const float* Wg2 = (const float*)d_in[15];
  const float* bg2 = (const float*)d_in[16];
  const float* Wq = (const float*)d_in[17];
  const float* Wk = (const float*)d_in[18];
  const float* Wv = (const float*)d_in[19];

  char* ws = (char*)d_ws;
  int* knn = (int*)ws;                                  // 1 MB
  float* pre = (float*)(ws + (1 << 20));                // 8 MB
  float* qv = (float*)(ws + (9 << 20));                 // 8 MB
  float* kv = (float*)(ws + (17 << 20));                // 8 MB
  float* vv = (float*)(ws + (25 << 20));                // 8 MB
  float* res_ws = (float*)(ws + (33 << 20));            // 8 MB
  short* wsw = (short*)(ws + (41 << 20));               // 96 KB bf16 B-frags
  short* wsplit = (short*)(ws + (41 << 20) + (128 << 10));  // 384 KB split frags

  float* out_res = (float*)d_out;
  float* out_attn = out_res + (size_t)BN * DD;

  hipLaunchKernelGGL(swz_all_kernel, dim3(72), dim3(256), 0, stream, Wd2, Wg1,
                     Wg2, W0b, W1, Wq, Wk, Wv, W2, wsw, wsplit);
  hipLaunchKernelGGL(knn_kernel, dim3(1024), dim3(256), 0, stream, xyz, knn);
  hipLaunchKernelGGL(point_mlp_mfma_kernel, dim3(1024), dim3(256), 0, stream,
                     xyz, W0a, b0a, b0b, b1, wsplit, pre, qv, kv, vv);
  hipLaunchKernelGGL(attn_mfma_kernel, dim3(4096), dim3(256), 0, stream, xyz,
                     knn, qv, kv, vv, wsw, Wd1, bd1, bd2, bg1, bg2, res_ws,
                     out_attn);
  hipLaunchKernelGGL(epilogue_mfma_kernel, dim3(1024), dim3(256), 0, stream,
                     res_ws, wsplit, b2, pre, out_res);
}